// Round 8
// baseline (302.492 us; speedup 1.0000x reference)
//
#include <hip/hip_runtime.h>

#define NF 128      // feature width for x / hidden layers
#define CHUNK 4096  // edges per block in CSR-build phase 1

typedef __attribute__((ext_vector_type(8))) short bf16x8;
typedef __attribute__((ext_vector_type(4))) float f32x4;
typedef __attribute__((ext_vector_type(2))) float f32x2;

__device__ __forceinline__ unsigned short f2b(float f) {
    unsigned int u = __float_as_uint(f);
    unsigned int r = (u + 0x7fffu + ((u >> 16) & 1u)) >> 16;  // round-nearest-even
    return (unsigned short)r;
}

// async global->LDS, 16B per lane. LDS dest = wave-uniform base (+lane*16 by HW);
// global src is per-lane.
__device__ __forceinline__ void gld_lds16(const void* g, const void* l) {
    __builtin_amdgcn_global_load_lds(
        (const __attribute__((address_space(1))) unsigned int*)(unsigned long long)g,
        (__attribute__((address_space(3))) unsigned int*)(unsigned int)(unsigned long long)l,
        16, 0, 0);
}

// ========== fused prep: cvt | wcat0 | wcat1 | wstack | hist (block ranges) ====

__global__ __launch_bounds__(256) void prep_kernel(
        const float* __restrict__ x, unsigned short* __restrict__ xb, int n4,
        const float* __restrict__ Wl0, const float* __restrict__ Wr0, unsigned short* __restrict__ Wc0,
        const float* __restrict__ Wl1, const float* __restrict__ Wr1, unsigned short* __restrict__ Wc1,
        const float* __restrict__ Wl2, const float* __restrict__ Wr2, const float* __restrict__ b2,
        unsigned short* __restrict__ Wst, float* __restrict__ bst,
        const int* __restrict__ dst, int* __restrict__ hist, int E, int NB,
        int bCvt, int bW0, int bW1, int bWs) {
    __shared__ int hsh[512];
    const int blk = blockIdx.x;
    const int tid = threadIdx.x;
    if (blk < bCvt) {
        int i = blk * 256 + tid;
        if (i < n4) {
            float4 v = *(const float4*)&x[(size_t)i * 4];
            uint2 o;
            o.x = (unsigned int)f2b(v.x) | ((unsigned int)f2b(v.y) << 16);
            o.y = (unsigned int)f2b(v.z) | ((unsigned int)f2b(v.w) << 16);
            *(uint2*)&xb[(size_t)i * 4] = o;
        }
    } else if (blk < bW1) {
        const bool first = blk < bW0;
        int i = (blk - (first ? bCvt : bW0)) * 256 + tid;  // < 16384
        const float* Wl = first ? Wl0 : Wl1;
        const float* Wr = first ? Wr0 : Wr1;
        unsigned short* Wc = first ? Wc0 : Wc1;
        int f = i >> 7, k = i & 127;
        Wc[f * 256 + k] = f2b(Wl[i]);
        Wc[f * 256 + 128 + k] = f2b(Wr[i]);
    } else if (blk < bWs) {
        int i = (blk - bW1) * 256 + tid;  // < 8192
        int f = i >> 7, k = i & 127;
        Wst[f * 128 + k] = f2b(Wl2[i]);
        Wst[(f + 64) * 128 + k] = f2b(Wr2[i]);
        if (k == 0) {
            bst[f] = 0.f;
            bst[f + 64] = b2[f];
        }
    } else {
        const int hb = blk - bWs;  // hist block
        for (int i = tid; i < NB; i += 256) hsh[i] = 0;
        __syncthreads();
        const int e0 = hb * CHUNK;
        for (int i = tid; i < CHUNK; i += 256) {
            int e = e0 + i;
            if (e < E) atomicAdd(&hsh[dst[e] >> 8], 1);
        }
        __syncthreads();
        for (int i = tid; i < NB; i += 256) hist[hb * NB + i] = hsh[i];
    }
}

// ================= CSR build scan chain =================

__global__ __launch_bounds__(256) void sb_sum(const int* __restrict__ hist,
                                              int* __restrict__ bsum,
                                              int T, int NB, int NBLK) {
    int i = blockIdx.x * 256 + threadIdx.x;
    int v = 0;
    if (i < T) {
        int b = i / NBLK, blk = i - b * NBLK;
        v = hist[blk * NB + b];
    }
#pragma unroll
    for (int d = 32; d; d >>= 1) v += __shfl_down(v, d, 64);
    __shared__ int wsum[4];
    if ((threadIdx.x & 63) == 0) wsum[threadIdx.x >> 6] = v;
    __syncthreads();
    if (threadIdx.x == 0) bsum[blockIdx.x] = wsum[0] + wsum[1] + wsum[2] + wsum[3];
}

__global__ __launch_bounds__(1024) void sb_scan(const int* __restrict__ bsum,
                                                int* __restrict__ bpre, int NS) {
    __shared__ int s[1024];
    int t = threadIdx.x;
    int v = (t < NS) ? bsum[t] : 0;
    s[t] = v;
    __syncthreads();
    for (int d = 1; d < 1024; d <<= 1) {
        int u = (t >= d) ? s[t - d] : 0;
        __syncthreads();
        s[t] += u;
        __syncthreads();
    }
    if (t < NS) bpre[t] = s[t] - v;
}

// sb_apply + bstart fused
__global__ __launch_bounds__(256) void sb_apply(const int* __restrict__ hist,
                                                const int* __restrict__ bpre,
                                                int* __restrict__ base,
                                                int* __restrict__ bstart,
                                                int T, int NB, int NBLK, int E) {
    __shared__ int s[256];
    int i = blockIdx.x * 256 + threadIdx.x;
    int t = threadIdx.x;
    int v = 0;
    int b = 0, blk = 0;
    if (i < T) {
        b = i / NBLK;
        blk = i - b * NBLK;
        v = hist[blk * NB + b];
    }
    s[t] = v;
    __syncthreads();
    for (int d = 1; d < 256; d <<= 1) {
        int u = (t >= d) ? s[t - d] : 0;
        __syncthreads();
        s[t] += u;
        __syncthreads();
    }
    if (i < T) {
        int val = bpre[blockIdx.x] + s[t] - v;
        base[i] = val;
        if (blk == 0) bstart[b] = val;       // bucket start
        if (i == 0) bstart[NB] = E;
    }
}

__global__ __launch_bounds__(256) void scat_kernel(const int* __restrict__ src,
                                                   const int* __restrict__ dst,
                                                   const int* __restrict__ base,
                                                   unsigned int* __restrict__ recs,
                                                   int E, int NB, int NBLK) {
    __shared__ int cur[512];
    const int blk = blockIdx.x;
    for (int b = threadIdx.x; b < NB; b += 256) cur[b] = base[b * NBLK + blk];
    __syncthreads();
    const int e0 = blk * CHUNK;
    for (int i = threadIdx.x; i < CHUNK; i += 256) {
        int e = e0 + i;
        if (e >= E) continue;
        int d = dst[e];
        int b = d >> 8;
        int pos = atomicAdd(&cur[b], 1);
        recs[pos] = (unsigned int)src[e] | ((unsigned int)(d & 255) << 24);
    }
}

__global__ __launch_bounds__(256) void csr_kernel(const unsigned int* __restrict__ recs,
                                                  const int* __restrict__ bstart,
                                                  int* __restrict__ offs,
                                                  float* __restrict__ rdeg,
                                                  int* __restrict__ csr,
                                                  int N, int E) {
    __shared__ int cnt[256];
    __shared__ int sc[256];
    __shared__ int cur[256];
    const int b = blockIdx.x;
    const int t = threadIdx.x;
    const int s0 = bstart[b], s1 = bstart[b + 1];
    cnt[t] = 0;
    __syncthreads();
    for (int i = s0 + t; i < s1; i += 256) atomicAdd(&cnt[recs[i] >> 24], 1);
    __syncthreads();
    int v = cnt[t];
    sc[t] = v;
    __syncthreads();
    for (int d = 1; d < 256; d <<= 1) {
        int u = (t >= d) ? sc[t - d] : 0;
        __syncthreads();
        sc[t] += u;
        __syncthreads();
    }
    int excl = sc[t] - v;
    int node = b * 256 + t;
    if (node < N) {
        offs[node] = s0 + excl;
        rdeg[node] = 1.0f / (float)(v > 1 ? v : 1);
        if (node == N - 1) offs[N] = E;
    }
    cur[t] = s0 + excl;
    __syncthreads();
    for (int i = s0 + t; i < s1; i += 256) {
        unsigned int r = recs[i];
        int pos = atomicAdd(&cur[r >> 24], 1);
        csr[pos] = (int)(r & 0xFFFFFFu);
    }
}

// -------- mean aggregation (bf16 in/out): one node/wave, full-row loads -------
// saddr addressing: unsigned 32-bit voffset off a uniform base -> 1 VALU/edge.

__global__ __launch_bounds__(256) void agg_kernel(
        const unsigned short* __restrict__ h, const int* __restrict__ offs,
        const int* __restrict__ csr, const float* __restrict__ rdeg,
        unsigned short* __restrict__ meanout, int N) {
    const int node = blockIdx.x * 4 + (threadIdx.x >> 6);
    const int lane = threadIdx.x & 63;
    if (node >= N) return;
    const int s0 = offs[node], s1 = offs[node + 1];
    const char* __restrict__ hb = (const char*)h;
    const unsigned lane4 = (unsigned)lane * 4u;
    f32x2 acc = {0.f, 0.f};
    for (int base = s0; base < s1; base += 64) {
        const int cnt = min(64, s1 - base);
        const int boff = csr[base + min(lane, cnt - 1)] << 8;  // row byte offset
        for (int j = 0; j < cnt; j += 16) {
            if (j + 16 <= cnt) {
                unsigned o[16];
#pragma unroll
                for (int k = 0; k < 16; ++k)
                    o[k] = (unsigned)__shfl(boff, j + k, 64) + lane4;
                unsigned int v[16];
#pragma unroll
                for (int k = 0; k < 16; ++k)
                    v[k] = *(const unsigned int*)(hb + o[k]);
#pragma unroll
                for (int k = 0; k < 16; ++k)
                    acc += (f32x2){__uint_as_float(v[k] << 16),
                                   __uint_as_float(v[k] & 0xffff0000u)};
            } else {
                unsigned o[16];
#pragma unroll
                for (int k = 0; k < 16; ++k)
                    o[k] = (unsigned)__shfl(boff, min(j + k, cnt - 1), 64) + lane4;
                unsigned int v[16];
#pragma unroll
                for (int k = 0; k < 16; ++k)
                    v[k] = *(const unsigned int*)(hb + o[k]);
#pragma unroll
                for (int k = 0; k < 16; ++k)
                    if (j + k < cnt)
                        acc += (f32x2){__uint_as_float(v[k] << 16),
                                       __uint_as_float(v[k] & 0xffff0000u)};
            }
        }
    }
    float r = rdeg[node];
    unsigned int o = (unsigned int)f2b(acc.x * r) | ((unsigned int)f2b(acc.y * r) << 16);
    *(unsigned int*)&meanout[(size_t)node * NF + lane * 2] = o;
}

// ---- layer-2 final agg: out[i] = mean_j zl[j] + zr[i]; one node/wave ---------

__global__ __launch_bounds__(256) void agg2_kernel(
        const unsigned short* __restrict__ z, const int* __restrict__ offs,
        const int* __restrict__ csr, const float* __restrict__ rdeg,
        float* __restrict__ out, int N) {
    const int node = blockIdx.x * 4 + (threadIdx.x >> 6);
    const int lane = threadIdx.x & 63;
    if (node >= N) return;
    const int hlf = lane >> 5;
    const int fl  = lane & 31;
    const int s0 = offs[node], s1 = offs[node + 1];
    const char* __restrict__ zb = (const char*)z;
    const unsigned fl4 = (unsigned)fl * 4u;
    f32x2 acc = {0.f, 0.f};
    for (int base = s0; base < s1; base += 64) {
        const int cnt = min(64, s1 - base);
        const int boff = csr[base + min(lane, cnt - 1)] << 8;
        for (int j = 0; j < cnt; j += 16) {
            if (j + 16 <= cnt) {
                unsigned o[8];
#pragma unroll
                for (int k = 0; k < 8; ++k)
                    o[k] = (unsigned)__shfl(boff, j + 2 * k + hlf, 64) + fl4;
                unsigned int v[8];
#pragma unroll
                for (int k = 0; k < 8; ++k)
                    v[k] = *(const unsigned int*)(zb + o[k]);
#pragma unroll
                for (int k = 0; k < 8; ++k)
                    acc += (f32x2){__uint_as_float(v[k] << 16),
                                   __uint_as_float(v[k] & 0xffff0000u)};
            } else {
                unsigned o[8];
#pragma unroll
                for (int k = 0; k < 8; ++k)
                    o[k] = (unsigned)__shfl(boff, min(j + 2 * k + hlf, cnt - 1), 64) + fl4;
                unsigned int v[8];
#pragma unroll
                for (int k = 0; k < 8; ++k)
                    v[k] = *(const unsigned int*)(zb + o[k]);
#pragma unroll
                for (int k = 0; k < 8; ++k)
                    if (j + 2 * k + hlf < cnt)
                        acc += (f32x2){__uint_as_float(v[k] << 16),
                                       __uint_as_float(v[k] & 0xffff0000u)};
            }
        }
    }
    acc.x += __shfl_xor(acc.x, 32, 64);
    acc.y += __shfl_xor(acc.y, 32, 64);
    if (hlf == 0) {
        float r = rdeg[node];
        unsigned int vr = *(const unsigned int*)(zb + (size_t)node * 256 + 128 + fl * 4);
        float2 o;
        o.x = acc.x * r + __uint_as_float(vr << 16);
        o.y = acc.y * r + __uint_as_float(vr & 0xffff0000u);
        *(float2*)&out[(size_t)node * 64 + fl * 2] = o;
    }
}

// ------- MFMA GEMM (layers 0/1): out = [mean|h] @ Wcat^T + b, relu, bf16 out ---
// A tile in LDS (gld_lds16, pre-swizzled source); W read DIRECT from global
// (64KB, L1/L2-hot) -> LDS 64KB -> 2 blocks/CU.

template <int FOUT, bool RELU>
__global__ __launch_bounds__(256) void gemm_kernel(
        const unsigned short* __restrict__ Abuf,   // mean [N][128] bf16
        const unsigned short* __restrict__ Hbuf,   // root [N][128] bf16
        const unsigned short* __restrict__ Wcat,   // [FOUT][256] bf16
        const float* __restrict__ bias,            // [FOUT] fp32
        unsigned short* __restrict__ outb,
        int N) {
    __shared__ unsigned short As[128 * 256];

    const int tid = threadIdx.x, wid = tid >> 6, lane = tid & 63;
    const int m0 = blockIdx.x * 128;
    char* Ac = (char*)As;
    const char* Ab = (const char*)Abuf;
    const char* Hb = (const char*)Hbuf;
    const char* Wb = (const char*)Wcat;

#pragma unroll
    for (int i = 0; i < 16; ++i) {
        int off = wid * 16384 + i * 1024 + lane * 16;
        int row = off >> 9, c = off & 511;
        int c2 = c ^ ((row & 7) << 4);
        const char* srcp = (c2 < 256) ? (Ab + (size_t)(m0 + row) * 256 + c2)
                                      : (Hb + (size_t)(m0 + row) * 256 + (c2 - 256));
        gld_lds16(srcp, Ac + wid * 16384 + i * 1024);
    }
    asm volatile("s_waitcnt vmcnt(0)" ::: "memory");
    __syncthreads();

    constexpr int MI = (FOUT == 128) ? 4 : 2;
    constexpr int NI = 4;
    const int lm = lane & 15, ko = lane >> 4;
    const int wmBase = (FOUT == 128) ? (wid >> 1) * 64 : wid * 32;
    const int wnBase = (FOUT == 128) ? (wid & 1) * 64 : 0;

    f32x4 acc[MI][NI];
#pragma unroll
    for (int i = 0; i < MI; ++i)
#pragma unroll
        for (int j = 0; j < NI; ++j)
            acc[i][j] = (f32x4){0.f, 0.f, 0.f, 0.f};

#pragma unroll
    for (int ks = 0; ks < 8; ++ks) {
        const int kb = ks * 64 + ko * 16;
        bf16x8 a[MI], b[NI];
#pragma unroll
        for (int j = 0; j < NI; ++j) {
            int row = wnBase + j * 16 + lm;
            b[j] = *(const bf16x8*)(Wb + row * 512 + kb);   // direct global (hot)
        }
#pragma unroll
        for (int i = 0; i < MI; ++i) {
            int row = wmBase + i * 16 + lm;
            a[i] = *(const bf16x8*)(Ac + row * 512 + (kb ^ ((row & 7) << 4)));
        }
#pragma unroll
        for (int i = 0; i < MI; ++i)
#pragma unroll
            for (int j = 0; j < NI; ++j)
                acc[i][j] = __builtin_amdgcn_mfma_f32_16x16x32_bf16(b[j], a[i], acc[i][j], 0, 0, 0);
    }

#pragma unroll
    for (int i = 0; i < MI; ++i) {
        const int node = m0 + wmBase + i * 16 + lm;
        if (node < N) {
#pragma unroll
            for (int j = 0; j < NI; ++j) {
                const int col0 = wnBase + j * 16 + ko * 4;
                const float4 bv = *(const float4*)&bias[col0];
                float v0 = acc[i][j][0] + bv.x;
                float v1 = acc[i][j][1] + bv.y;
                float v2 = acc[i][j][2] + bv.z;
                float v3 = acc[i][j][3] + bv.w;
                if (RELU) {
                    v0 = fmaxf(v0, 0.f); v1 = fmaxf(v1, 0.f);
                    v2 = fmaxf(v2, 0.f); v3 = fmaxf(v3, 0.f);
                }
                uint2 o;
                o.x = (unsigned int)f2b(v0) | ((unsigned int)f2b(v1) << 16);
                o.y = (unsigned int)f2b(v2) | ((unsigned int)f2b(v3) << 16);
                *(uint2*)&outb[(size_t)node * FOUT + col0] = o;
            }
        }
    }
}

// ---------- MFMA GEMM (layer 2): z = h @ Wst^T + bst  (K=128, bf16 out) -------

__global__ __launch_bounds__(256) void gemmz_kernel(
        const unsigned short* __restrict__ A,    // [N][128] bf16
        const unsigned short* __restrict__ W,    // [128][128] bf16
        const float* __restrict__ bias,          // [128] fp32
        unsigned short* __restrict__ outb,       // [N][128] bf16
        int N) {
    __shared__ unsigned short As[128 * 128];

    const int tid = threadIdx.x, wid = tid >> 6, lane = tid & 63;
    const int m0 = blockIdx.x * 128;
    char* Ac = (char*)As;
    const char* Ab = (const char*)A;
    const char* Wb = (const char*)W;

#pragma unroll
    for (int i = 0; i < 8; ++i) {
        int off = wid * 8192 + i * 1024 + lane * 16;
        int row = off >> 8, c = off & 255;
        int c2 = c ^ ((row & 7) << 4);
        gld_lds16(Ab + (size_t)(m0 + row) * 256 + c2, Ac + wid * 8192 + i * 1024);
    }
    asm volatile("s_waitcnt vmcnt(0)" ::: "memory");
    __syncthreads();

    const int lm = lane & 15, ko = lane >> 4;
    const int wmBase = (wid >> 1) * 64;
    const int wnBase = (wid & 1) * 64;

    f32x4 acc[4][4];
#pragma unroll
    for (int i = 0; i < 4; ++i)
#pragma unroll
        for (int j = 0; j < 4; ++j)
            acc[i][j] = (f32x4){0.f, 0.f, 0.f, 0.f};

#pragma unroll
    for (int ks = 0; ks < 4; ++ks) {
        const int kb = ks * 64 + ko * 16;
        bf16x8 a[4], b[4];
#pragma unroll
        for (int j = 0; j < 4; ++j) {
            int row = wnBase + j * 16 + lm;
            b[j] = *(const bf16x8*)(Wb + row * 256 + kb);   // direct global (hot)
        }
#pragma unroll
        for (int i = 0; i < 4; ++i) {
            int row = wmBase + i * 16 + lm;
            a[i] = *(const bf16x8*)(Ac + row * 256 + (kb ^ ((row & 7) << 4)));
        }
#pragma unroll
        for (int i = 0; i < 4; ++i)
#pragma unroll
            for (int j = 0; j < 4; ++j)
                acc[i][j] = __builtin_amdgcn_mfma_f32_16x16x32_bf16(b[j], a[i], acc[i][j], 0, 0, 0);
    }

#pragma unroll
    for (int i = 0; i < 4; ++i) {
        const int node = m0 + wmBase + i * 16 + lm;
        if (node < N) {
#pragma unroll
            for (int j = 0; j < 4; ++j) {
                const int col0 = wnBase + j * 16 + ko * 4;
                const float4 bv = *(const float4*)&bias[col0];
                uint2 o;
                o.x = (unsigned int)f2b(acc[i][j][0] + bv.x) |
                      ((unsigned int)f2b(acc[i][j][1] + bv.y) << 16);
                o.y = (unsigned int)f2b(acc[i][j][2] + bv.z) |
                      ((unsigned int)f2b(acc[i][j][3] + bv.w) << 16);
                *(uint2*)&outb[(size_t)node * 128 + col0] = o;
            }
        }
    }
}

// ---------------- launch ----------------

extern "C" void kernel_launch(void* const* d_in, const int* in_sizes, int n_in,
                              void* d_out, int out_size, void* d_ws, size_t ws_size,
                              hipStream_t stream) {
    const float* x   = (const float*)d_in[0];
    const int*   ei  = (const int*)d_in[1];
    const float* Wl0 = (const float*)d_in[2];
    const float* Wr0 = (const float*)d_in[3];
    const float* b0  = (const float*)d_in[4];
    const float* Wl1 = (const float*)d_in[5];
    const float* Wr1 = (const float*)d_in[6];
    const float* b1  = (const float*)d_in[7];
    const float* Wl2 = (const float*)d_in[8];
    const float* Wr2 = (const float*)d_in[9];
    const float* b2  = (const float*)d_in[10];
    float* out = (float*)d_out;

    const int N = in_sizes[0] / NF;
    const int E = in_sizes[1] / 2;
    const int* srcv = ei;
    const int* dstv = ei + E;

    const int NB   = (N + 255) >> 8;
    const int NBLK = (E + CHUNK - 1) / CHUNK;
    const int T    = NB * NBLK;
    const int NS   = (T + 255) / 256;

    char* w = (char*)d_ws;
    auto alloc = [&](size_t bytes) {
        void* p = (void*)w;
        w += (bytes + 255) & ~(size_t)255;
        return p;
    };
    unsigned short* xb   = (unsigned short*)alloc((size_t)N * NF * 2);
    unsigned short* h1b  = (unsigned short*)alloc((size_t)N * NF * 2);
    unsigned short* h2b  = (unsigned short*)alloc((size_t)N * NF * 2);
    unsigned short* mb   = (unsigned short*)alloc((size_t)N * NF * 2);
    unsigned short* z2b  = (unsigned short*)alloc((size_t)N * NF * 2);
    unsigned short* Wc0  = (unsigned short*)alloc((size_t)128 * 256 * 2);
    unsigned short* Wc1  = (unsigned short*)alloc((size_t)128 * 256 * 2);
    unsigned short* Wst2 = (unsigned short*)alloc((size_t)128 * 128 * 2);
    float*          bst2 = (float*)alloc((size_t)128 * 4);
    int*   offs   = (int*)alloc((size_t)(N + 1) * 4);
    int*   csr    = (int*)alloc((size_t)E * 4);
    float* rdeg   = (float*)alloc((size_t)N * 4);
    unsigned int* recs = (unsigned int*)alloc((size_t)E * 4);
    int*   hist   = (int*)alloc((size_t)T * 4);
    int*   base   = (int*)alloc((size_t)T * 4);
    int*   bstart = (int*)alloc((size_t)(NB + 1) * 4);
    int*   sb1    = (int*)alloc((size_t)1024 * 4);
    int*   sb2    = (int*)alloc((size_t)1024 * 4);

    const int n4 = N * NF / 4;
    const int bCvt = (n4 + 255) / 256;
    const int bW0  = bCvt + 64;            // wcat0: 16384/256
    const int bW1  = bW0 + 64;             // wcat1
    const int bWs  = bW1 + 32;             // wstack: 8192/256
    const int bTot = bWs + NBLK;           // + hist

    prep_kernel<<<bTot, 256, 0, stream>>>(x, xb, n4,
                                          Wl0, Wr0, Wc0, Wl1, Wr1, Wc1,
                                          Wl2, Wr2, b2, Wst2, bst2,
                                          dstv, hist, E, NB,
                                          bCvt, bW0, bW1, bWs);
    sb_sum<<<NS, 256, 0, stream>>>(hist, sb1, T, NB, NBLK);
    sb_scan<<<1, 1024, 0, stream>>>(sb1, sb2, NS);
    sb_apply<<<NS, 256, 0, stream>>>(hist, sb2, base, bstart, T, NB, NBLK, E);
    scat_kernel<<<NBLK, 256, 0, stream>>>(srcv, dstv, base, recs, E, NB, NBLK);
    csr_kernel<<<NB, 256, 0, stream>>>(recs, bstart, offs, rdeg, csr, N, E);

    const int ab = (N + 3) / 4;
    const int gb = (N + 127) / 128;

    agg_kernel<<<ab, 256, 0, stream>>>(xb, offs, csr, rdeg, mb, N);
    gemm_kernel<128, true><<<gb, 256, 0, stream>>>(mb, xb, Wc0, b0, h1b, N);

    agg_kernel<<<ab, 256, 0, stream>>>(h1b, offs, csr, rdeg, mb, N);
    gemm_kernel<128, true><<<gb, 256, 0, stream>>>(mb, h1b, Wc1, b1, h2b, N);

    gemmz_kernel<<<gb, 256, 0, stream>>>(h2b, Wst2, bst2, z2b, N);
    agg2_kernel<<<ab, 256, 0, stream>>>(z2b, offs, csr, rdeg, out, N);
}

// Round 9
// 297.967 us; speedup vs baseline: 1.0152x; 1.0152x over previous
//
#include <hip/hip_runtime.h>

#define NF 128      // feature width for x / hidden layers
#define CHUNK 8192  // edges per block in CSR-build phase 1

typedef __attribute__((ext_vector_type(8))) short bf16x8;
typedef __attribute__((ext_vector_type(4))) float f32x4;
typedef __attribute__((ext_vector_type(2))) float f32x2;

__device__ __forceinline__ unsigned short f2b(float f) {
    unsigned int u = __float_as_uint(f);
    unsigned int r = (u + 0x7fffu + ((u >> 16) & 1u)) >> 16;  // round-nearest-even
    return (unsigned short)r;
}

// async global->LDS, 16B per lane. LDS dest = wave-uniform base (+lane*16 by HW);
// global src is per-lane.
__device__ __forceinline__ void gld_lds16(const void* g, const void* l) {
    __builtin_amdgcn_global_load_lds(
        (const __attribute__((address_space(1))) unsigned int*)(unsigned long long)g,
        (__attribute__((address_space(3))) unsigned int*)(unsigned int)(unsigned long long)l,
        16, 0, 0);
}

// ========== fused prep: cvt(+fp8) | wcat0 | wcat1 | wstack | hist ============

__global__ __launch_bounds__(256) void prep_kernel(
        const float* __restrict__ x, unsigned short* __restrict__ xb,
        unsigned char* __restrict__ x8, int n4,
        const float* __restrict__ Wl0, const float* __restrict__ Wr0, unsigned short* __restrict__ Wc0,
        const float* __restrict__ Wl1, const float* __restrict__ Wr1, unsigned short* __restrict__ Wc1,
        const float* __restrict__ Wl2, const float* __restrict__ Wr2, const float* __restrict__ b2,
        unsigned short* __restrict__ Wst, float* __restrict__ bst,
        const int* __restrict__ dst, int* __restrict__ hist, int E, int NB,
        int bCvt, int bW0, int bW1, int bWs) {
    __shared__ int hsh[512];
    const int blk = blockIdx.x;
    const int tid = threadIdx.x;
    if (blk < bCvt) {
        int i = blk * 256 + tid;
        if (i < n4) {
            float4 v = *(const float4*)&x[(size_t)i * 4];
            uint2 o;
            o.x = (unsigned int)f2b(v.x) | ((unsigned int)f2b(v.y) << 16);
            o.y = (unsigned int)f2b(v.z) | ((unsigned int)f2b(v.w) << 16);
            *(uint2*)&xb[(size_t)i * 4] = o;
            unsigned p = __builtin_amdgcn_cvt_pk_fp8_f32(v.x, v.y, 0, false);
            p = __builtin_amdgcn_cvt_pk_fp8_f32(v.z, v.w, p, true);
            *(unsigned int*)&x8[(size_t)i * 4] = p;
        }
    } else if (blk < bW1) {
        const bool first = blk < bW0;
        int i = (blk - (first ? bCvt : bW0)) * 256 + tid;  // < 16384
        const float* Wl = first ? Wl0 : Wl1;
        const float* Wr = first ? Wr0 : Wr1;
        unsigned short* Wc = first ? Wc0 : Wc1;
        int f = i >> 7, k = i & 127;
        Wc[f * 256 + k] = f2b(Wl[i]);
        Wc[f * 256 + 128 + k] = f2b(Wr[i]);
    } else if (blk < bWs) {
        int i = (blk - bW1) * 256 + tid;  // < 8192
        int f = i >> 7, k = i & 127;
        Wst[f * 128 + k] = f2b(Wl2[i]);
        Wst[(f + 64) * 128 + k] = f2b(Wr2[i]);
        if (k == 0) {
            bst[f] = 0.f;
            bst[f + 64] = b2[f];
        }
    } else {
        const int hb = blk - bWs;  // hist block
        for (int i = tid; i < NB; i += 256) hsh[i] = 0;
        __syncthreads();
        const int e0 = hb * CHUNK;
        for (int i = tid; i < CHUNK; i += 256) {
            int e = e0 + i;
            if (e < E) atomicAdd(&hsh[dst[e] >> 8], 1);
        }
        __syncthreads();
        for (int i = tid; i < NB; i += 256) hist[hb * NB + i] = hsh[i];
    }
}

// ---------- bf16 -> fp8 copy (for layer-1 gather) ----------

__global__ __launch_bounds__(256) void cvt8_kernel(const unsigned short* __restrict__ in,
                                                   unsigned char* __restrict__ out8, int n8) {
    int i = blockIdx.x * 256 + threadIdx.x;  // 8 elems per thread
    if (i >= n8) return;
    uint4 v = *(const uint4*)&in[(size_t)i * 8];
    float f0 = __uint_as_float(v.x << 16), f1 = __uint_as_float(v.x & 0xffff0000u);
    float f2 = __uint_as_float(v.y << 16), f3 = __uint_as_float(v.y & 0xffff0000u);
    float f4 = __uint_as_float(v.z << 16), f5 = __uint_as_float(v.z & 0xffff0000u);
    float f6 = __uint_as_float(v.w << 16), f7 = __uint_as_float(v.w & 0xffff0000u);
    unsigned lo = __builtin_amdgcn_cvt_pk_fp8_f32(f0, f1, 0, false);
    lo = __builtin_amdgcn_cvt_pk_fp8_f32(f2, f3, lo, true);
    unsigned hi = __builtin_amdgcn_cvt_pk_fp8_f32(f4, f5, 0, false);
    hi = __builtin_amdgcn_cvt_pk_fp8_f32(f6, f7, hi, true);
    uint2 o = make_uint2(lo, hi);
    *(uint2*)&out8[(size_t)i * 8] = o;
}

// ================= CSR build scan chain =================

__global__ __launch_bounds__(256) void sb_sum(const int* __restrict__ hist,
                                              int* __restrict__ bsum,
                                              int T, int NB, int NBLK) {
    int i = blockIdx.x * 256 + threadIdx.x;
    int v = 0;
    if (i < T) {
        int b = i / NBLK, blk = i - b * NBLK;
        v = hist[blk * NB + b];
    }
#pragma unroll
    for (int d = 32; d; d >>= 1) v += __shfl_down(v, d, 64);
    __shared__ int wsum[4];
    if ((threadIdx.x & 63) == 0) wsum[threadIdx.x >> 6] = v;
    __syncthreads();
    if (threadIdx.x == 0) bsum[blockIdx.x] = wsum[0] + wsum[1] + wsum[2] + wsum[3];
}

__global__ __launch_bounds__(1024) void sb_scan(const int* __restrict__ bsum,
                                                int* __restrict__ bpre, int NS) {
    __shared__ int s[1024];
    int t = threadIdx.x;
    int v = (t < NS) ? bsum[t] : 0;
    s[t] = v;
    __syncthreads();
    for (int d = 1; d < 1024; d <<= 1) {
        int u = (t >= d) ? s[t - d] : 0;
        __syncthreads();
        s[t] += u;
        __syncthreads();
    }
    if (t < NS) bpre[t] = s[t] - v;
}

__global__ __launch_bounds__(256) void sb_apply(const int* __restrict__ hist,
                                                const int* __restrict__ bpre,
                                                int* __restrict__ base,
                                                int* __restrict__ bstart,
                                                int T, int NB, int NBLK, int E) {
    __shared__ int s[256];
    int i = blockIdx.x * 256 + threadIdx.x;
    int t = threadIdx.x;
    int v = 0;
    int b = 0, blk = 0;
    if (i < T) {
        b = i / NBLK;
        blk = i - b * NBLK;
        v = hist[blk * NB + b];
    }
    s[t] = v;
    __syncthreads();
    for (int d = 1; d < 256; d <<= 1) {
        int u = (t >= d) ? s[t - d] : 0;
        __syncthreads();
        s[t] += u;
        __syncthreads();
    }
    if (i < T) {
        int val = bpre[blockIdx.x] + s[t] - v;
        base[i] = val;
        if (blk == 0) bstart[b] = val;
        if (i == 0) bstart[NB] = E;
    }
}

__global__ __launch_bounds__(256) void scat_kernel(const int* __restrict__ src,
                                                   const int* __restrict__ dst,
                                                   const int* __restrict__ base,
                                                   unsigned int* __restrict__ recs,
                                                   int E, int NB, int NBLK) {
    __shared__ int cur[512];
    const int blk = blockIdx.x;
    for (int b = threadIdx.x; b < NB; b += 256) cur[b] = base[b * NBLK + blk];
    __syncthreads();
    const int e0 = blk * CHUNK;
    for (int i = threadIdx.x; i < CHUNK; i += 256) {
        int e = e0 + i;
        if (e >= E) continue;
        int d = dst[e];
        int b = d >> 8;
        int pos = atomicAdd(&cur[b], 1);
        recs[pos] = (unsigned int)src[e] | ((unsigned int)(d & 255) << 24);
    }
}

__global__ __launch_bounds__(256) void csr_kernel(const unsigned int* __restrict__ recs,
                                                  const int* __restrict__ bstart,
                                                  int* __restrict__ offs,
                                                  float* __restrict__ rdeg,
                                                  int* __restrict__ csr,
                                                  int N, int E) {
    __shared__ int cnt[256];
    __shared__ int sc[256];
    __shared__ int cur[256];
    const int b = blockIdx.x;
    const int t = threadIdx.x;
    const int s0 = bstart[b], s1 = bstart[b + 1];
    cnt[t] = 0;
    __syncthreads();
    for (int i = s0 + t; i < s1; i += 256) atomicAdd(&cnt[recs[i] >> 24], 1);
    __syncthreads();
    int v = cnt[t];
    sc[t] = v;
    __syncthreads();
    for (int d = 1; d < 256; d <<= 1) {
        int u = (t >= d) ? sc[t - d] : 0;
        __syncthreads();
        sc[t] += u;
        __syncthreads();
    }
    int excl = sc[t] - v;
    int node = b * 256 + t;
    if (node < N) {
        offs[node] = s0 + excl;
        rdeg[node] = 1.0f / (float)(v > 1 ? v : 1);
        if (node == N - 1) offs[N] = E;
    }
    cur[t] = s0 + excl;
    __syncthreads();
    for (int i = s0 + t; i < s1; i += 256) {
        unsigned int r = recs[i];
        int pos = atomicAdd(&cur[r >> 24], 1);
        csr[pos] = (int)(r & 0xFFFFFFu);
    }
}

// -------- mean aggregation from FP8 rows (128B/row), bf16 mean out -----------
// One node per wave; full-row loads (64 lanes x 2B); 16 loads in flight.

__global__ __launch_bounds__(256) void agg8_kernel(
        const unsigned char* __restrict__ h8, const int* __restrict__ offs,
        const int* __restrict__ csr, const float* __restrict__ rdeg,
        unsigned short* __restrict__ meanout, int N) {
    const int node = blockIdx.x * 4 + (threadIdx.x >> 6);
    const int lane = threadIdx.x & 63;
    if (node >= N) return;
    const int s0 = offs[node], s1 = offs[node + 1];
    const char* __restrict__ hb = (const char*)h8;
    const unsigned lane2 = (unsigned)lane * 2u;
    f32x2 acc = {0.f, 0.f};
    for (int base = s0; base < s1; base += 64) {
        const int cnt = min(64, s1 - base);
        const int boff = csr[base + min(lane, cnt - 1)] << 7;  // fp8 row byte offset
        for (int j = 0; j < cnt; j += 16) {
            if (j + 16 <= cnt) {
                unsigned o[16];
#pragma unroll
                for (int k = 0; k < 16; ++k)
                    o[k] = (unsigned)__shfl(boff, j + k, 64) + lane2;
                unsigned int v[16];
#pragma unroll
                for (int k = 0; k < 16; ++k)
                    v[k] = *(const unsigned short*)(hb + o[k]);
#pragma unroll
                for (int k = 0; k < 16; ++k) {
                    acc.x += __builtin_amdgcn_cvt_f32_fp8(v[k], 0);
                    acc.y += __builtin_amdgcn_cvt_f32_fp8(v[k], 1);
                }
            } else {
                unsigned o[16];
#pragma unroll
                for (int k = 0; k < 16; ++k)
                    o[k] = (unsigned)__shfl(boff, min(j + k, cnt - 1), 64) + lane2;
                unsigned int v[16];
#pragma unroll
                for (int k = 0; k < 16; ++k)
                    v[k] = *(const unsigned short*)(hb + o[k]);
#pragma unroll
                for (int k = 0; k < 16; ++k)
                    if (j + k < cnt) {
                        acc.x += __builtin_amdgcn_cvt_f32_fp8(v[k], 0);
                        acc.y += __builtin_amdgcn_cvt_f32_fp8(v[k], 1);
                    }
            }
        }
    }
    float r = rdeg[node];
    unsigned int o = (unsigned int)f2b(acc.x * r) | ((unsigned int)f2b(acc.y * r) << 16);
    *(unsigned int*)&meanout[(size_t)node * NF + lane * 2] = o;
}

// ---- layer-2 final agg (bf16 zl rows): out[i] = mean_j zl[j] + zr[i] --------

__global__ __launch_bounds__(256) void agg2_kernel(
        const unsigned short* __restrict__ z, const int* __restrict__ offs,
        const int* __restrict__ csr, const float* __restrict__ rdeg,
        float* __restrict__ out, int N) {
    const int node = blockIdx.x * 4 + (threadIdx.x >> 6);
    const int lane = threadIdx.x & 63;
    if (node >= N) return;
    const int hlf = lane >> 5;
    const int fl  = lane & 31;
    const int s0 = offs[node], s1 = offs[node + 1];
    const char* __restrict__ zb = (const char*)z;
    const unsigned fl4 = (unsigned)fl * 4u;
    f32x2 acc = {0.f, 0.f};
    for (int base = s0; base < s1; base += 64) {
        const int cnt = min(64, s1 - base);
        const int boff = csr[base + min(lane, cnt - 1)] << 8;
        for (int j = 0; j < cnt; j += 16) {
            if (j + 16 <= cnt) {
                unsigned o[8];
#pragma unroll
                for (int k = 0; k < 8; ++k)
                    o[k] = (unsigned)__shfl(boff, j + 2 * k + hlf, 64) + fl4;
                unsigned int v[8];
#pragma unroll
                for (int k = 0; k < 8; ++k)
                    v[k] = *(const unsigned int*)(zb + o[k]);
#pragma unroll
                for (int k = 0; k < 8; ++k)
                    acc += (f32x2){__uint_as_float(v[k] << 16),
                                   __uint_as_float(v[k] & 0xffff0000u)};
            } else {
                unsigned o[8];
#pragma unroll
                for (int k = 0; k < 8; ++k)
                    o[k] = (unsigned)__shfl(boff, min(j + 2 * k + hlf, cnt - 1), 64) + fl4;
                unsigned int v[8];
#pragma unroll
                for (int k = 0; k < 8; ++k)
                    v[k] = *(const unsigned int*)(zb + o[k]);
#pragma unroll
                for (int k = 0; k < 8; ++k)
                    if (j + 2 * k + hlf < cnt)
                        acc += (f32x2){__uint_as_float(v[k] << 16),
                                       __uint_as_float(v[k] & 0xffff0000u)};
            }
        }
    }
    acc.x += __shfl_xor(acc.x, 32, 64);
    acc.y += __shfl_xor(acc.y, 32, 64);
    if (hlf == 0) {
        float r = rdeg[node];
        unsigned int vr = *(const unsigned int*)(zb + (size_t)node * 256 + 128 + fl * 4);
        float2 o;
        o.x = acc.x * r + __uint_as_float(vr << 16);
        o.y = acc.y * r + __uint_as_float(vr & 0xffff0000u);
        *(float2*)&out[(size_t)node * 64 + fl * 2] = o;
    }
}

// ------- MFMA GEMM (layers 0/1): out = [mean|h] @ Wcat^T + b, relu, bf16 out ---

template <int FOUT, bool RELU>
__global__ __launch_bounds__(256) void gemm_kernel(
        const unsigned short* __restrict__ Abuf,   // mean [N][128] bf16
        const unsigned short* __restrict__ Hbuf,   // root [N][128] bf16
        const unsigned short* __restrict__ Wcat,   // [FOUT][256] bf16
        const float* __restrict__ bias,            // [FOUT] fp32
        unsigned short* __restrict__ outb,
        int N) {
    __shared__ unsigned short As[128 * 256];

    const int tid = threadIdx.x, wid = tid >> 6, lane = tid & 63;
    const int m0 = blockIdx.x * 128;
    char* Ac = (char*)As;
    const char* Ab = (const char*)Abuf;
    const char* Hb = (const char*)Hbuf;
    const char* Wb = (const char*)Wcat;

#pragma unroll
    for (int i = 0; i < 16; ++i) {
        int off = wid * 16384 + i * 1024 + lane * 16;
        int row = off >> 9, c = off & 511;
        int c2 = c ^ ((row & 7) << 4);
        const char* srcp = (c2 < 256) ? (Ab + (size_t)(m0 + row) * 256 + c2)
                                      : (Hb + (size_t)(m0 + row) * 256 + (c2 - 256));
        gld_lds16(srcp, Ac + wid * 16384 + i * 1024);
    }
    asm volatile("s_waitcnt vmcnt(0)" ::: "memory");
    __syncthreads();

    constexpr int MI = (FOUT == 128) ? 4 : 2;
    constexpr int NI = 4;
    const int lm = lane & 15, ko = lane >> 4;
    const int wmBase = (FOUT == 128) ? (wid >> 1) * 64 : wid * 32;
    const int wnBase = (FOUT == 128) ? (wid & 1) * 64 : 0;

    f32x4 acc[MI][NI];
#pragma unroll
    for (int i = 0; i < MI; ++i)
#pragma unroll
        for (int j = 0; j < NI; ++j)
            acc[i][j] = (f32x4){0.f, 0.f, 0.f, 0.f};

#pragma unroll
    for (int ks = 0; ks < 8; ++ks) {
        const int kb = ks * 64 + ko * 16;
        bf16x8 a[MI], b[NI];
#pragma unroll
        for (int j = 0; j < NI; ++j) {
            int row = wnBase + j * 16 + lm;
            b[j] = *(const bf16x8*)(Wb + row * 512 + kb);   // direct global (hot)
        }
#pragma unroll
        for (int i = 0; i < MI; ++i) {
            int row = wmBase + i * 16 + lm;
            a[i] = *(const bf16x8*)(Ac + row * 512 + (kb ^ ((row & 7) << 4)));
        }
#pragma unroll
        for (int i = 0; i < MI; ++i)
#pragma unroll
            for (int j = 0; j < NI; ++j)
                acc[i][j] = __builtin_amdgcn_mfma_f32_16x16x32_bf16(b[j], a[i], acc[i][j], 0, 0, 0);
    }

#pragma unroll
    for (int i = 0; i < MI; ++i) {
        const int node = m0 + wmBase + i * 16 + lm;
        if (node < N) {
#pragma unroll
            for (int j = 0; j < NI; ++j) {
                const int col0 = wnBase + j * 16 + ko * 4;
                const float4 bv = *(const float4*)&bias[col0];
                float v0 = acc[i][j][0] + bv.x;
                float v1 = acc[i][j][1] + bv.y;
                float v2 = acc[i][j][2] + bv.z;
                float v3 = acc[i][j][3] + bv.w;
                if (RELU) {
                    v0 = fmaxf(v0, 0.f); v1 = fmaxf(v1, 0.f);
                    v2 = fmaxf(v2, 0.f); v3 = fmaxf(v3, 0.f);
                }
                uint2 o;
                o.x = (unsigned int)f2b(v0) | ((unsigned int)f2b(v1) << 16);
                o.y = (unsigned int)f2b(v2) | ((unsigned int)f2b(v3) << 16);
                *(uint2*)&outb[(size_t)node * FOUT + col0] = o;
            }
        }
    }
}

// ---------- MFMA GEMM (layer 2): z = h @ Wst^T + bst  (K=128, bf16 out) -------

__global__ __launch_bounds__(256) void gemmz_kernel(
        const unsigned short* __restrict__ A,    // [N][128] bf16
        const unsigned short* __restrict__ W,    // [128][128] bf16
        const float* __restrict__ bias,          // [128] fp32
        unsigned short* __restrict__ outb,       // [N][128] bf16
        int N) {
    __shared__ unsigned short As[128 * 128];

    const int tid = threadIdx.x, wid = tid >> 6, lane = tid & 63;
    const int m0 = blockIdx.x * 128;
    char* Ac = (char*)As;
    const char* Ab = (const char*)A;
    const char* Wb = (const char*)W;

#pragma unroll
    for (int i = 0; i < 8; ++i) {
        int off = wid * 8192 + i * 1024 + lane * 16;
        int row = off >> 8, c = off & 255;
        int c2 = c ^ ((row & 7) << 4);
        gld_lds16(Ab + (size_t)(m0 + row) * 256 + c2, Ac + wid * 8192 + i * 1024);
    }
    asm volatile("s_waitcnt vmcnt(0)" ::: "memory");
    __syncthreads();

    const int lm = lane & 15, ko = lane >> 4;
    const int wmBase = (wid >> 1) * 64;
    const int wnBase = (wid & 1) * 64;

    f32x4 acc[4][4];
#pragma unroll
    for (int i = 0; i < 4; ++i)
#pragma unroll
        for (int j = 0; j < 4; ++j)
            acc[i][j] = (f32x4){0.f, 0.f, 0.f, 0.f};

#pragma unroll
    for (int ks = 0; ks < 4; ++ks) {
        const int kb = ks * 64 + ko * 16;
        bf16x8 a[4], b[4];
#pragma unroll
        for (int j = 0; j < 4; ++j) {
            int row = wnBase + j * 16 + lm;
            b[j] = *(const bf16x8*)(Wb + row * 256 + kb);   // direct global (hot)
        }
#pragma unroll
        for (int i = 0; i < 4; ++i) {
            int row = wmBase + i * 16 + lm;
            a[i] = *(const bf16x8*)(Ac + row * 256 + (kb ^ ((row & 7) << 4)));
        }
#pragma unroll
        for (int i = 0; i < 4; ++i)
#pragma unroll
            for (int j = 0; j < 4; ++j)
                acc[i][j] = __builtin_amdgcn_mfma_f32_16x16x32_bf16(b[j], a[i], acc[i][j], 0, 0, 0);
    }

#pragma unroll
    for (int i = 0; i < 4; ++i) {
        const int node = m0 + wmBase + i * 16 + lm;
        if (node < N) {
#pragma unroll
            for (int j = 0; j < 4; ++j) {
                const int col0 = wnBase + j * 16 + ko * 4;
                const float4 bv = *(const float4*)&bias[col0];
                uint2 o;
                o.x = (unsigned int)f2b(acc[i][j][0] + bv.x) |
                      ((unsigned int)f2b(acc[i][j][1] + bv.y) << 16);
                o.y = (unsigned int)f2b(acc[i][j][2] + bv.z) |
                      ((unsigned int)f2b(acc[i][j][3] + bv.w) << 16);
                *(uint2*)&outb[(size_t)node * 128 + col0] = o;
            }
        }
    }
}

// ---------------- launch ----------------

extern "C" void kernel_launch(void* const* d_in, const int* in_sizes, int n_in,
                              void* d_out, int out_size, void* d_ws, size_t ws_size,
                              hipStream_t stream) {
    const float* x   = (const float*)d_in[0];
    const int*   ei  = (const int*)d_in[1];
    const float* Wl0 = (const float*)d_in[2];
    const float* Wr0 = (const float*)d_in[3];
    const float* b0  = (const float*)d_in[4];
    const float* Wl1 = (const float*)d_in[5];
    const float* Wr1 = (const float*)d_in[6];
    const float* b1  = (const float*)d_in[7];
    const float* Wl2 = (const float*)d_in[8];
    const float* Wr2 = (const float*)d_in[9];
    const float* b2  = (const float*)d_in[10];
    float* out = (float*)d_out;

    const int N = in_sizes[0] / NF;
    const int E = in_sizes[1] / 2;
    const int* srcv = ei;
    const int* dstv = ei + E;

    const int NB   = (N + 255) >> 8;
    const int NBLK = (E + CHUNK - 1) / CHUNK;
    const int T    = NB * NBLK;
    const int NS   = (T + 255) / 256;

    char* w = (char*)d_ws;
    auto alloc = [&](size_t bytes) {
        void* p = (void*)w;
        w += (bytes + 255) & ~(size_t)255;
        return p;
    };
    unsigned short* xb   = (unsigned short*)alloc((size_t)N * NF * 2);
    unsigned short* h1b  = (unsigned short*)alloc((size_t)N * NF * 2);
    unsigned short* h2b  = (unsigned short*)alloc((size_t)N * NF * 2);
    unsigned short* mb   = (unsigned short*)alloc((size_t)N * NF * 2);
    // fp8 region (25.6 MB): x8 + h18 while live; z2b aliases it afterwards
    unsigned char*  u8   = (unsigned char*)alloc((size_t)N * NF * 2);
    unsigned char*  x8   = u8;                       // [N][128] fp8
    unsigned char*  h18  = u8 + (size_t)N * NF;      // [N][128] fp8
    unsigned short* z2b  = (unsigned short*)u8;      // [N][128] bf16 (after x8/h18 dead)
    unsigned short* Wc0  = (unsigned short*)alloc((size_t)128 * 256 * 2);
    unsigned short* Wc1  = (unsigned short*)alloc((size_t)128 * 256 * 2);
    unsigned short* Wst2 = (unsigned short*)alloc((size_t)128 * 128 * 2);
    float*          bst2 = (float*)alloc((size_t)128 * 4);
    int*   offs   = (int*)alloc((size_t)(N + 1) * 4);
    int*   csr    = (int*)alloc((size_t)E * 4);
    float* rdeg   = (float*)alloc((size_t)N * 4);
    unsigned int* recs = (unsigned int*)alloc((size_t)E * 4);
    int*   hist   = (int*)alloc((size_t)T * 4);
    int*   base   = (int*)alloc((size_t)T * 4);
    int*   bstart = (int*)alloc((size_t)(NB + 1) * 4);
    int*   sb1    = (int*)alloc((size_t)1024 * 4);
    int*   sb2    = (int*)alloc((size_t)1024 * 4);

    const int n4 = N * NF / 4;
    const int bCvt = (n4 + 255) / 256;
    const int bW0  = bCvt + 64;            // wcat0: 16384/256
    const int bW1  = bW0 + 64;             // wcat1
    const int bWs  = bW1 + 32;             // wstack: 8192/256
    const int bTot = bWs + NBLK;           // + hist

    prep_kernel<<<bTot, 256, 0, stream>>>(x, xb, x8, n4,
                                          Wl0, Wr0, Wc0, Wl1, Wr1, Wc1,
                                          Wl2, Wr2, b2, Wst2, bst2,
                                          dstv, hist, E, NB,
                                          bCvt, bW0, bW1, bWs);
    sb_sum<<<NS, 256, 0, stream>>>(hist, sb1, T, NB, NBLK);
    sb_scan<<<1, 1024, 0, stream>>>(sb1, sb2, NS);
    sb_apply<<<NS, 256, 0, stream>>>(hist, sb2, base, bstart, T, NB, NBLK, E);
    scat_kernel<<<NBLK, 256, 0, stream>>>(srcv, dstv, base, recs, E, NB, NBLK);
    csr_kernel<<<NB, 256, 0, stream>>>(recs, bstart, offs, rdeg, csr, N, E);

    const int ab = (N + 3) / 4;
    const int gb = (N + 127) / 128;
    const int n8 = N * NF / 8;

    // layer 0: mean from fp8 x, root bf16 x
    agg8_kernel<<<ab, 256, 0, stream>>>(x8, offs, csr, rdeg, mb, N);
    gemm_kernel<128, true><<<gb, 256, 0, stream>>>(mb, xb, Wc0, b0, h1b, N);

    // layer 1: fp8 copy of h1, mean from it, root bf16 h1
    cvt8_kernel<<<(n8 + 255) / 256, 256, 0, stream>>>(h1b, h18, n8);
    agg8_kernel<<<ab, 256, 0, stream>>>(h18, offs, csr, rdeg, mb, N);
    gemm_kernel<128, true><<<gb, 256, 0, stream>>>(mb, h1b, Wc1, b1, h2b, N);

    // layer 2: transform-first (bf16), fused final agg
    gemmz_kernel<<<gb, 256, 0, stream>>>(h2b, Wst2, bst2, z2b, N);
    agg2_kernel<<<ab, 256, 0, stream>>>(z2b, offs, csr, rdeg, out, N);
}

// Round 10
// 295.988 us; speedup vs baseline: 1.0220x; 1.0067x over previous
//
#include <hip/hip_runtime.h>

#define NF 128      // feature width for x / hidden layers
#define CHUNK 8192  // edges per block in CSR-build phase 1

typedef __attribute__((ext_vector_type(8))) short bf16x8;
typedef __attribute__((ext_vector_type(4))) float f32x4;
typedef __attribute__((ext_vector_type(2))) float f32x2;

__device__ __forceinline__ unsigned short f2b(float f) {
    unsigned int u = __float_as_uint(f);
    unsigned int r = (u + 0x7fffu + ((u >> 16) & 1u)) >> 16;  // round-nearest-even
    return (unsigned short)r;
}

// async global->LDS, 16B per lane. LDS dest = wave-uniform base (+lane*16 by HW);
// global src is per-lane.
__device__ __forceinline__ void gld_lds16(const void* g, const void* l) {
    __builtin_amdgcn_global_load_lds(
        (const __attribute__((address_space(1))) unsigned int*)(unsigned long long)g,
        (__attribute__((address_space(3))) unsigned int*)(unsigned int)(unsigned long long)l,
        16, 0, 0);
}

// ========== fused prep: cvt(+fp8) | wcat0 | wcat1 | wstack | hist ============

__global__ __launch_bounds__(256) void prep_kernel(
        const float* __restrict__ x, unsigned short* __restrict__ xb,
        unsigned char* __restrict__ x8, int n4,
        const float* __restrict__ Wl0, const float* __restrict__ Wr0, unsigned short* __restrict__ Wc0,
        const float* __restrict__ Wl1, const float* __restrict__ Wr1, unsigned short* __restrict__ Wc1,
        const float* __restrict__ Wl2, const float* __restrict__ Wr2, const float* __restrict__ b2,
        unsigned short* __restrict__ Wst, float* __restrict__ bst,
        const int* __restrict__ dst, int* __restrict__ hist, int E, int NB,
        int bCvt, int bW0, int bW1, int bWs) {
    __shared__ int hsh[512];
    const int blk = blockIdx.x;
    const int tid = threadIdx.x;
    if (blk < bCvt) {
        int i = blk * 256 + tid;
        if (i < n4) {
            float4 v = *(const float4*)&x[(size_t)i * 4];
            uint2 o;
            o.x = (unsigned int)f2b(v.x) | ((unsigned int)f2b(v.y) << 16);
            o.y = (unsigned int)f2b(v.z) | ((unsigned int)f2b(v.w) << 16);
            *(uint2*)&xb[(size_t)i * 4] = o;
            unsigned p = __builtin_amdgcn_cvt_pk_fp8_f32(v.x, v.y, 0, false);
            p = __builtin_amdgcn_cvt_pk_fp8_f32(v.z, v.w, p, true);
            *(unsigned int*)&x8[(size_t)i * 4] = p;
        }
    } else if (blk < bW1) {
        const bool first = blk < bW0;
        int i = (blk - (first ? bCvt : bW0)) * 256 + tid;  // < 16384
        const float* Wl = first ? Wl0 : Wl1;
        const float* Wr = first ? Wr0 : Wr1;
        unsigned short* Wc = first ? Wc0 : Wc1;
        int f = i >> 7, k = i & 127;
        Wc[f * 256 + k] = f2b(Wl[i]);
        Wc[f * 256 + 128 + k] = f2b(Wr[i]);
    } else if (blk < bWs) {
        int i = (blk - bW1) * 256 + tid;  // < 8192
        int f = i >> 7, k = i & 127;
        Wst[f * 128 + k] = f2b(Wl2[i]);
        Wst[(f + 64) * 128 + k] = f2b(Wr2[i]);
        if (k == 0) {
            bst[f] = 0.f;
            bst[f + 64] = b2[f];
        }
    } else {
        const int hb = blk - bWs;  // hist block
        for (int i = tid; i < NB; i += 256) hsh[i] = 0;
        __syncthreads();
        const int e0 = hb * CHUNK;
        for (int i = tid; i < CHUNK; i += 256) {
            int e = e0 + i;
            if (e < E) atomicAdd(&hsh[dst[e] >> 8], 1);
        }
        __syncthreads();
        for (int i = tid; i < NB; i += 256) hist[hb * NB + i] = hsh[i];
    }
}

// ================= CSR build scan chain =================

__global__ __launch_bounds__(256) void sb_sum(const int* __restrict__ hist,
                                              int* __restrict__ bsum,
                                              int T, int NB, int NBLK) {
    int i = blockIdx.x * 256 + threadIdx.x;
    int v = 0;
    if (i < T) {
        int b = i / NBLK, blk = i - b * NBLK;
        v = hist[blk * NB + b];
    }
#pragma unroll
    for (int d = 32; d; d >>= 1) v += __shfl_down(v, d, 64);
    __shared__ int wsum[4];
    if ((threadIdx.x & 63) == 0) wsum[threadIdx.x >> 6] = v;
    __syncthreads();
    if (threadIdx.x == 0) bsum[blockIdx.x] = wsum[0] + wsum[1] + wsum[2] + wsum[3];
}

__global__ __launch_bounds__(1024) void sb_scan(const int* __restrict__ bsum,
                                                int* __restrict__ bpre, int NS) {
    __shared__ int s[1024];
    int t = threadIdx.x;
    int v = (t < NS) ? bsum[t] : 0;
    s[t] = v;
    __syncthreads();
    for (int d = 1; d < 1024; d <<= 1) {
        int u = (t >= d) ? s[t - d] : 0;
        __syncthreads();
        s[t] += u;
        __syncthreads();
    }
    if (t < NS) bpre[t] = s[t] - v;
}

__global__ __launch_bounds__(256) void sb_apply(const int* __restrict__ hist,
                                                const int* __restrict__ bpre,
                                                int* __restrict__ base,
                                                int* __restrict__ bstart,
                                                int T, int NB, int NBLK, int E) {
    __shared__ int s[256];
    int i = blockIdx.x * 256 + threadIdx.x;
    int t = threadIdx.x;
    int v = 0;
    int b = 0, blk = 0;
    if (i < T) {
        b = i / NBLK;
        blk = i - b * NBLK;
        v = hist[blk * NB + b];
    }
    s[t] = v;
    __syncthreads();
    for (int d = 1; d < 256; d <<= 1) {
        int u = (t >= d) ? s[t - d] : 0;
        __syncthreads();
        s[t] += u;
        __syncthreads();
    }
    if (i < T) {
        int val = bpre[blockIdx.x] + s[t] - v;
        base[i] = val;
        if (blk == 0) bstart[b] = val;
        if (i == 0) bstart[NB] = E;
    }
}

__global__ __launch_bounds__(256) void scat_kernel(const int* __restrict__ src,
                                                   const int* __restrict__ dst,
                                                   const int* __restrict__ base,
                                                   unsigned int* __restrict__ recs,
                                                   int E, int NB, int NBLK) {
    __shared__ int cur[512];
    const int blk = blockIdx.x;
    for (int b = threadIdx.x; b < NB; b += 256) cur[b] = base[b * NBLK + blk];
    __syncthreads();
    const int e0 = blk * CHUNK;
    for (int i = threadIdx.x; i < CHUNK; i += 256) {
        int e = e0 + i;
        if (e >= E) continue;
        int d = dst[e];
        int b = d >> 8;
        int pos = atomicAdd(&cur[b], 1);
        recs[pos] = (unsigned int)src[e] | ((unsigned int)(d & 255) << 24);
    }
}

__global__ __launch_bounds__(256) void csr_kernel(const unsigned int* __restrict__ recs,
                                                  const int* __restrict__ bstart,
                                                  int* __restrict__ offs,
                                                  float* __restrict__ rdeg,
                                                  int* __restrict__ csr,
                                                  int N, int E) {
    __shared__ int cnt[256];
    __shared__ int sc[256];
    __shared__ int cur[256];
    const int b = blockIdx.x;
    const int t = threadIdx.x;
    const int s0 = bstart[b], s1 = bstart[b + 1];
    cnt[t] = 0;
    __syncthreads();
    for (int i = s0 + t; i < s1; i += 256) atomicAdd(&cnt[recs[i] >> 24], 1);
    __syncthreads();
    int v = cnt[t];
    sc[t] = v;
    __syncthreads();
    for (int d = 1; d < 256; d <<= 1) {
        int u = (t >= d) ? sc[t - d] : 0;
        __syncthreads();
        sc[t] += u;
        __syncthreads();
    }
    int excl = sc[t] - v;
    int node = b * 256 + t;
    if (node < N) {
        offs[node] = s0 + excl;
        rdeg[node] = 1.0f / (float)(v > 1 ? v : 1);
        if (node == N - 1) offs[N] = E;
    }
    cur[t] = s0 + excl;
    __syncthreads();
    for (int i = s0 + t; i < s1; i += 256) {
        unsigned int r = recs[i];
        int pos = atomicAdd(&cur[r >> 24], 1);
        csr[pos] = (int)(r & 0xFFFFFFu);
    }
}

// -------- mean aggregation from FP8 rows (128B/row), bf16 mean out -----------
// One node per wave; full-row loads; pk-convert (2 fp8 -> 2 f32, 1 instr).

__global__ __launch_bounds__(256) void agg8_kernel(
        const unsigned char* __restrict__ h8, const int* __restrict__ offs,
        const int* __restrict__ csr, const float* __restrict__ rdeg,
        unsigned short* __restrict__ meanout, int N) {
    const int node = blockIdx.x * 4 + (threadIdx.x >> 6);
    const int lane = threadIdx.x & 63;
    if (node >= N) return;
    const int s0 = offs[node], s1 = offs[node + 1];
    const char* __restrict__ hb = (const char*)h8;
    const unsigned lane2 = (unsigned)lane * 2u;
    f32x2 acc = {0.f, 0.f};
    for (int base = s0; base < s1; base += 64) {
        const int cnt = min(64, s1 - base);
        const int boff = csr[base + min(lane, cnt - 1)] << 7;  // fp8 row byte offset
        for (int j = 0; j < cnt; j += 16) {
            if (j + 16 <= cnt) {
                unsigned o[16];
#pragma unroll
                for (int k = 0; k < 16; ++k)
                    o[k] = (unsigned)__shfl(boff, j + k, 64) + lane2;
                unsigned int v[16];
#pragma unroll
                for (int k = 0; k < 16; ++k)
                    v[k] = *(const unsigned short*)(hb + o[k]);
#pragma unroll
                for (int k = 0; k < 16; ++k) {
                    f32x2 pr = __builtin_amdgcn_cvt_pk_f32_fp8(v[k], false);
                    acc += pr;
                }
            } else {
                unsigned o[16];
#pragma unroll
                for (int k = 0; k < 16; ++k)
                    o[k] = (unsigned)__shfl(boff, min(j + k, cnt - 1), 64) + lane2;
                unsigned int v[16];
#pragma unroll
                for (int k = 0; k < 16; ++k)
                    v[k] = *(const unsigned short*)(hb + o[k]);
#pragma unroll
                for (int k = 0; k < 16; ++k)
                    if (j + k < cnt) {
                        f32x2 pr = __builtin_amdgcn_cvt_pk_f32_fp8(v[k], false);
                        acc += pr;
                    }
            }
        }
    }
    float r = rdeg[node];
    unsigned int o = (unsigned int)f2b(acc.x * r) | ((unsigned int)f2b(acc.y * r) << 16);
    *(unsigned int*)&meanout[(size_t)node * NF + lane * 2] = o;
}

// ---- layer-2 final agg (bf16 zl rows): out[i] = mean_j zl[j] + zr[i] --------

__global__ __launch_bounds__(256) void agg2_kernel(
        const unsigned short* __restrict__ z, const int* __restrict__ offs,
        const int* __restrict__ csr, const float* __restrict__ rdeg,
        float* __restrict__ out, int N) {
    const int node = blockIdx.x * 4 + (threadIdx.x >> 6);
    const int lane = threadIdx.x & 63;
    if (node >= N) return;
    const int hlf = lane >> 5;
    const int fl  = lane & 31;
    const int s0 = offs[node], s1 = offs[node + 1];
    const char* __restrict__ zb = (const char*)z;
    const unsigned fl4 = (unsigned)fl * 4u;
    f32x2 acc = {0.f, 0.f};
    for (int base = s0; base < s1; base += 64) {
        const int cnt = min(64, s1 - base);
        const int boff = csr[base + min(lane, cnt - 1)] << 8;
        for (int j = 0; j < cnt; j += 16) {
            if (j + 16 <= cnt) {
                unsigned o[8];
#pragma unroll
                for (int k = 0; k < 8; ++k)
                    o[k] = (unsigned)__shfl(boff, j + 2 * k + hlf, 64) + fl4;
                unsigned int v[8];
#pragma unroll
                for (int k = 0; k < 8; ++k)
                    v[k] = *(const unsigned int*)(zb + o[k]);
#pragma unroll
                for (int k = 0; k < 8; ++k)
                    acc += (f32x2){__uint_as_float(v[k] << 16),
                                   __uint_as_float(v[k] & 0xffff0000u)};
            } else {
                unsigned o[8];
#pragma unroll
                for (int k = 0; k < 8; ++k)
                    o[k] = (unsigned)__shfl(boff, min(j + 2 * k + hlf, cnt - 1), 64) + fl4;
                unsigned int v[8];
#pragma unroll
                for (int k = 0; k < 8; ++k)
                    v[k] = *(const unsigned int*)(zb + o[k]);
#pragma unroll
                for (int k = 0; k < 8; ++k)
                    if (j + 2 * k + hlf < cnt)
                        acc += (f32x2){__uint_as_float(v[k] << 16),
                                       __uint_as_float(v[k] & 0xffff0000u)};
            }
        }
    }
    acc.x += __shfl_xor(acc.x, 32, 64);
    acc.y += __shfl_xor(acc.y, 32, 64);
    if (hlf == 0) {
        float r = rdeg[node];
        unsigned int vr = *(const unsigned int*)(zb + (size_t)node * 256 + 128 + fl * 4);
        float2 o;
        o.x = acc.x * r + __uint_as_float(vr << 16);
        o.y = acc.y * r + __uint_as_float(vr & 0xffff0000u);
        *(float2*)&out[(size_t)node * 64 + fl * 2] = o;
    }
}

// ------- MFMA GEMM (layers 0/1): out = [mean|h] @ Wcat^T + b, relu, bf16 out ---
// OUT8: additionally emit fp8 rows of the output (for next layer's gather).

template <int FOUT, bool RELU, bool OUT8>
__global__ __launch_bounds__(256) void gemm_kernel(
        const unsigned short* __restrict__ Abuf,   // mean [N][128] bf16
        const unsigned short* __restrict__ Hbuf,   // root [N][128] bf16
        const unsigned short* __restrict__ Wcat,   // [FOUT][256] bf16
        const float* __restrict__ bias,            // [FOUT] fp32
        unsigned short* __restrict__ outb,
        unsigned char* __restrict__ out8,
        int N) {
    __shared__ unsigned short As[128 * 256];

    const int tid = threadIdx.x, wid = tid >> 6, lane = tid & 63;
    const int m0 = blockIdx.x * 128;
    char* Ac = (char*)As;
    const char* Ab = (const char*)Abuf;
    const char* Hb = (const char*)Hbuf;
    const char* Wb = (const char*)Wcat;

#pragma unroll
    for (int i = 0; i < 16; ++i) {
        int off = wid * 16384 + i * 1024 + lane * 16;
        int row = off >> 9, c = off & 511;
        int c2 = c ^ ((row & 7) << 4);
        const char* srcp = (c2 < 256) ? (Ab + (size_t)(m0 + row) * 256 + c2)
                                      : (Hb + (size_t)(m0 + row) * 256 + (c2 - 256));
        gld_lds16(srcp, Ac + wid * 16384 + i * 1024);
    }
    asm volatile("s_waitcnt vmcnt(0)" ::: "memory");
    __syncthreads();

    constexpr int MI = (FOUT == 128) ? 4 : 2;
    constexpr int NI = 4;
    const int lm = lane & 15, ko = lane >> 4;
    const int wmBase = (FOUT == 128) ? (wid >> 1) * 64 : wid * 32;
    const int wnBase = (FOUT == 128) ? (wid & 1) * 64 : 0;

    f32x4 acc[MI][NI];
#pragma unroll
    for (int i = 0; i < MI; ++i)
#pragma unroll
        for (int j = 0; j < NI; ++j)
            acc[i][j] = (f32x4){0.f, 0.f, 0.f, 0.f};

#pragma unroll
    for (int ks = 0; ks < 8; ++ks) {
        const int kb = ks * 64 + ko * 16;
        bf16x8 a[MI], b[NI];
#pragma unroll
        for (int j = 0; j < NI; ++j) {
            int row = wnBase + j * 16 + lm;
            b[j] = *(const bf16x8*)(Wb + row * 512 + kb);   // direct global (hot)
        }
#pragma unroll
        for (int i = 0; i < MI; ++i) {
            int row = wmBase + i * 16 + lm;
            a[i] = *(const bf16x8*)(Ac + row * 512 + (kb ^ ((row & 7) << 4)));
        }
#pragma unroll
        for (int i = 0; i < MI; ++i)
#pragma unroll
            for (int j = 0; j < NI; ++j)
                acc[i][j] = __builtin_amdgcn_mfma_f32_16x16x32_bf16(b[j], a[i], acc[i][j], 0, 0, 0);
    }

#pragma unroll
    for (int i = 0; i < MI; ++i) {
        const int node = m0 + wmBase + i * 16 + lm;
        if (node < N) {
#pragma unroll
            for (int j = 0; j < NI; ++j) {
                const int col0 = wnBase + j * 16 + ko * 4;
                const float4 bv = *(const float4*)&bias[col0];
                float v0 = acc[i][j][0] + bv.x;
                float v1 = acc[i][j][1] + bv.y;
                float v2 = acc[i][j][2] + bv.z;
                float v3 = acc[i][j][3] + bv.w;
                if (RELU) {
                    v0 = fmaxf(v0, 0.f); v1 = fmaxf(v1, 0.f);
                    v2 = fmaxf(v2, 0.f); v3 = fmaxf(v3, 0.f);
                }
                uint2 o;
                o.x = (unsigned int)f2b(v0) | ((unsigned int)f2b(v1) << 16);
                o.y = (unsigned int)f2b(v2) | ((unsigned int)f2b(v3) << 16);
                *(uint2*)&outb[(size_t)node * FOUT + col0] = o;
                if (OUT8) {
                    unsigned p = __builtin_amdgcn_cvt_pk_fp8_f32(v0, v1, 0, false);
                    p = __builtin_amdgcn_cvt_pk_fp8_f32(v2, v3, p, true);
                    *(unsigned int*)&out8[(size_t)node * FOUT + col0] = p;
                }
            }
        }
    }
}

// ---------- MFMA GEMM (layer 2): z = h @ Wst^T + bst  (K=128, bf16 out) -------

__global__ __launch_bounds__(256) void gemmz_kernel(
        const unsigned short* __restrict__ A,    // [N][128] bf16
        const unsigned short* __restrict__ W,    // [128][128] bf16
        const float* __restrict__ bias,          // [128] fp32
        unsigned short* __restrict__ outb,       // [N][128] bf16
        int N) {
    __shared__ unsigned short As[128 * 128];

    const int tid = threadIdx.x, wid = tid >> 6, lane = tid & 63;
    const int m0 = blockIdx.x * 128;
    char* Ac = (char*)As;
    const char* Ab = (const char*)A;
    const char* Wb = (const char*)W;

#pragma unroll
    for (int i = 0; i < 8; ++i) {
        int off = wid * 8192 + i * 1024 + lane * 16;
        int row = off >> 8, c = off & 255;
        int c2 = c ^ ((row & 7) << 4);
        gld_lds16(Ab + (size_t)(m0 + row) * 256 + c2, Ac + wid * 8192 + i * 1024);
    }
    asm volatile("s_waitcnt vmcnt(0)" ::: "memory");
    __syncthreads();

    const int lm = lane & 15, ko = lane >> 4;
    const int wmBase = (wid >> 1) * 64;
    const int wnBase = (wid & 1) * 64;

    f32x4 acc[4][4];
#pragma unroll
    for (int i = 0; i < 4; ++i)
#pragma unroll
        for (int j = 0; j < 4; ++j)
            acc[i][j] = (f32x4){0.f, 0.f, 0.f, 0.f};

#pragma unroll
    for (int ks = 0; ks < 4; ++ks) {
        const int kb = ks * 64 + ko * 16;
        bf16x8 a[4], b[4];
#pragma unroll
        for (int j = 0; j < 4; ++j) {
            int row = wnBase + j * 16 + lm;
            b[j] = *(const bf16x8*)(Wb + row * 256 + kb);   // direct global (hot)
        }
#pragma unroll
        for (int i = 0; i < 4; ++i) {
            int row = wmBase + i * 16 + lm;
            a[i] = *(const bf16x8*)(Ac + row * 256 + (kb ^ ((row & 7) << 4)));
        }
#pragma unroll
        for (int i = 0; i < 4; ++i)
#pragma unroll
            for (int j = 0; j < 4; ++j)
                acc[i][j] = __builtin_amdgcn_mfma_f32_16x16x32_bf16(b[j], a[i], acc[i][j], 0, 0, 0);
    }

#pragma unroll
    for (int i = 0; i < 4; ++i) {
        const int node = m0 + wmBase + i * 16 + lm;
        if (node < N) {
#pragma unroll
            for (int j = 0; j < 4; ++j) {
                const int col0 = wnBase + j * 16 + ko * 4;
                const float4 bv = *(const float4*)&bias[col0];
                uint2 o;
                o.x = (unsigned int)f2b(acc[i][j][0] + bv.x) |
                      ((unsigned int)f2b(acc[i][j][1] + bv.y) << 16);
                o.y = (unsigned int)f2b(acc[i][j][2] + bv.z) |
                      ((unsigned int)f2b(acc[i][j][3] + bv.w) << 16);
                *(uint2*)&outb[(size_t)node * 128 + col0] = o;
            }
        }
    }
}

// ---------------- launch ----------------

extern "C" void kernel_launch(void* const* d_in, const int* in_sizes, int n_in,
                              void* d_out, int out_size, void* d_ws, size_t ws_size,
                              hipStream_t stream) {
    const float* x   = (const float*)d_in[0];
    const int*   ei  = (const int*)d_in[1];
    const float* Wl0 = (const float*)d_in[2];
    const float* Wr0 = (const float*)d_in[3];
    const float* b0  = (const float*)d_in[4];
    const float* Wl1 = (const float*)d_in[5];
    const float* Wr1 = (const float*)d_in[6];
    const float* b1  = (const float*)d_in[7];
    const float* Wl2 = (const float*)d_in[8];
    const float* Wr2 = (const float*)d_in[9];
    const float* b2  = (const float*)d_in[10];
    float* out = (float*)d_out;

    const int N = in_sizes[0] / NF;
    const int E = in_sizes[1] / 2;
    const int* srcv = ei;
    const int* dstv = ei + E;

    const int NB   = (N + 255) >> 8;
    const int NBLK = (E + CHUNK - 1) / CHUNK;
    const int T    = NB * NBLK;
    const int NS   = (T + 255) / 256;

    char* w = (char*)d_ws;
    auto alloc = [&](size_t bytes) {
        void* p = (void*)w;
        w += (bytes + 255) & ~(size_t)255;
        return p;
    };
    unsigned short* xb   = (unsigned short*)alloc((size_t)N * NF * 2);
    unsigned short* h1b  = (unsigned short*)alloc((size_t)N * NF * 2);
    unsigned short* h2b  = (unsigned short*)alloc((size_t)N * NF * 2);
    unsigned short* mb   = (unsigned short*)alloc((size_t)N * NF * 2);
    // fp8 region (25.6 MB): x8 + h18 while live; z2b aliases it afterwards
    unsigned char*  u8   = (unsigned char*)alloc((size_t)N * NF * 2);
    unsigned char*  x8   = u8;                       // [N][128] fp8
    unsigned char*  h18  = u8 + (size_t)N * NF;      // [N][128] fp8
    unsigned short* z2b  = (unsigned short*)u8;      // [N][128] bf16 (after x8/h18 dead)
    unsigned short* Wc0  = (unsigned short*)alloc((size_t)128 * 256 * 2);
    unsigned short* Wc1  = (unsigned short*)alloc((size_t)128 * 256 * 2);
    unsigned short* Wst2 = (unsigned short*)alloc((size_t)128 * 128 * 2);
    float*          bst2 = (float*)alloc((size_t)128 * 4);
    int*   offs   = (int*)alloc((size_t)(N + 1) * 4);
    int*   csr    = (int*)alloc((size_t)E * 4);
    float* rdeg   = (float*)alloc((size_t)N * 4);
    unsigned int* recs = (unsigned int*)alloc((size_t)E * 4);
    int*   hist   = (int*)alloc((size_t)T * 4);
    int*   base   = (int*)alloc((size_t)T * 4);
    int*   bstart = (int*)alloc((size_t)(NB + 1) * 4);
    int*   sb1    = (int*)alloc((size_t)1024 * 4);
    int*   sb2    = (int*)alloc((size_t)1024 * 4);

    const int n4 = N * NF / 4;
    const int bCvt = (n4 + 255) / 256;
    const int bW0  = bCvt + 64;            // wcat0: 16384/256
    const int bW1  = bW0 + 64;             // wcat1
    const int bWs  = bW1 + 32;             // wstack: 8192/256
    const int bTot = bWs + NBLK;           // + hist

    prep_kernel<<<bTot, 256, 0, stream>>>(x, xb, x8, n4,
                                          Wl0, Wr0, Wc0, Wl1, Wr1, Wc1,
                                          Wl2, Wr2, b2, Wst2, bst2,
                                          dstv, hist, E, NB,
                                          bCvt, bW0, bW1, bWs);
    sb_sum<<<NS, 256, 0, stream>>>(hist, sb1, T, NB, NBLK);
    sb_scan<<<1, 1024, 0, stream>>>(sb1, sb2, NS);
    sb_apply<<<NS, 256, 0, stream>>>(hist, sb2, base, bstart, T, NB, NBLK, E);
    scat_kernel<<<NBLK, 256, 0, stream>>>(srcv, dstv, base, recs, E, NB, NBLK);
    csr_kernel<<<NB, 256, 0, stream>>>(recs, bstart, offs, rdeg, csr, N, E);

    const int ab = (N + 3) / 4;
    const int gb = (N + 127) / 128;

    // layer 0: mean from fp8 x; gemm also emits fp8 h1 for next gather
    agg8_kernel<<<ab, 256, 0, stream>>>(x8, offs, csr, rdeg, mb, N);
    gemm_kernel<128, true, true><<<gb, 256, 0, stream>>>(mb, xb, Wc0, b0, h1b, h18, N);

    // layer 1: mean from fp8 h1, root bf16 h1
    agg8_kernel<<<ab, 256, 0, stream>>>(h18, offs, csr, rdeg, mb, N);
    gemm_kernel<128, true, false><<<gb, 256, 0, stream>>>(mb, h1b, Wc1, b1, h2b, nullptr, N);

    // layer 2: transform-first (bf16), fused final agg
    gemmz_kernel<<<gb, 256, 0, stream>>>(h2b, Wst2, bst2, z2b, N);
    agg2_kernel<<<ab, 256, 0, stream>>>(z2b, offs, csr, rdeg, out, N);
}

// Round 11
// 292.176 us; speedup vs baseline: 1.0353x; 1.0130x over previous
//
#include <hip/hip_runtime.h>

#define NF 128      // feature width for x / hidden layers
#define CHUNK 8192  // edges per block in CSR-build phase 1

typedef __attribute__((ext_vector_type(8))) short bf16x8;
typedef __attribute__((ext_vector_type(4))) float f32x4;
typedef __attribute__((ext_vector_type(2))) float f32x2;

__device__ __forceinline__ unsigned short f2b(float f) {
    unsigned int u = __float_as_uint(f);
    unsigned int r = (u + 0x7fffu + ((u >> 16) & 1u)) >> 16;  // round-nearest-even
    return (unsigned short)r;
}

// async global->LDS, 16B per lane. LDS dest = wave-uniform base (+lane*16 by HW);
// global src is per-lane.
__device__ __forceinline__ void gld_lds16(const void* g, const void* l) {
    __builtin_amdgcn_global_load_lds(
        (const __attribute__((address_space(1))) unsigned int*)(unsigned long long)g,
        (__attribute__((address_space(3))) unsigned int*)(unsigned int)(unsigned long long)l,
        16, 0, 0);
}

// ========== fused prep: cvt(+fp8) | wcat0 | wcat1 | wstack | hist ============

__global__ __launch_bounds__(256) void prep_kernel(
        const float* __restrict__ x, unsigned short* __restrict__ xb,
        unsigned char* __restrict__ x8, int n4,
        const float* __restrict__ Wl0, const float* __restrict__ Wr0, unsigned short* __restrict__ Wc0,
        const float* __restrict__ Wl1, const float* __restrict__ Wr1, unsigned short* __restrict__ Wc1,
        const float* __restrict__ Wl2, const float* __restrict__ Wr2, const float* __restrict__ b2,
        unsigned short* __restrict__ Wst, float* __restrict__ bst,
        const int* __restrict__ dst, int* __restrict__ hist, int E, int NB,
        int bCvt, int bW0, int bW1, int bWs) {
    __shared__ int hsh[512];
    const int blk = blockIdx.x;
    const int tid = threadIdx.x;
    if (blk < bCvt) {
        int i = blk * 256 + tid;
        if (i < n4) {
            float4 v = *(const float4*)&x[(size_t)i * 4];
            uint2 o;
            o.x = (unsigned int)f2b(v.x) | ((unsigned int)f2b(v.y) << 16);
            o.y = (unsigned int)f2b(v.z) | ((unsigned int)f2b(v.w) << 16);
            *(uint2*)&xb[(size_t)i * 4] = o;
            unsigned p = __builtin_amdgcn_cvt_pk_fp8_f32(v.x, v.y, 0, false);
            p = __builtin_amdgcn_cvt_pk_fp8_f32(v.z, v.w, p, true);
            *(unsigned int*)&x8[(size_t)i * 4] = p;
        }
    } else if (blk < bW1) {
        const bool first = blk < bW0;
        int i = (blk - (first ? bCvt : bW0)) * 256 + tid;  // < 16384
        const float* Wl = first ? Wl0 : Wl1;
        const float* Wr = first ? Wr0 : Wr1;
        unsigned short* Wc = first ? Wc0 : Wc1;
        int f = i >> 7, k = i & 127;
        Wc[f * 256 + k] = f2b(Wl[i]);
        Wc[f * 256 + 128 + k] = f2b(Wr[i]);
    } else if (blk < bWs) {
        int i = (blk - bW1) * 256 + tid;  // < 8192
        int f = i >> 7, k = i & 127;
        Wst[f * 128 + k] = f2b(Wl2[i]);
        Wst[(f + 64) * 128 + k] = f2b(Wr2[i]);
        if (k == 0) {
            bst[f] = 0.f;
            bst[f + 64] = b2[f];
        }
    } else {
        const int hb = blk - bWs;  // hist block
        for (int i = tid; i < NB; i += 256) hsh[i] = 0;
        __syncthreads();
        const int e0 = hb * CHUNK;
        for (int i = tid; i < CHUNK; i += 256) {
            int e = e0 + i;
            if (e < E) atomicAdd(&hsh[dst[e] >> 8], 1);
        }
        __syncthreads();
        for (int i = tid; i < NB; i += 256) hist[hb * NB + i] = hsh[i];
    }
}

// ================= CSR build scan chain =================

__global__ __launch_bounds__(256) void sb_sum(const int* __restrict__ hist,
                                              int* __restrict__ bsum,
                                              int T, int NB, int NBLK) {
    int i = blockIdx.x * 256 + threadIdx.x;
    int v = 0;
    if (i < T) {
        int b = i / NBLK, blk = i - b * NBLK;
        v = hist[blk * NB + b];
    }
#pragma unroll
    for (int d = 32; d; d >>= 1) v += __shfl_down(v, d, 64);
    __shared__ int wsum[4];
    if ((threadIdx.x & 63) == 0) wsum[threadIdx.x >> 6] = v;
    __syncthreads();
    if (threadIdx.x == 0) bsum[blockIdx.x] = wsum[0] + wsum[1] + wsum[2] + wsum[3];
}

__global__ __launch_bounds__(1024) void sb_scan(const int* __restrict__ bsum,
                                                int* __restrict__ bpre, int NS) {
    __shared__ int s[1024];
    int t = threadIdx.x;
    int v = (t < NS) ? bsum[t] : 0;
    s[t] = v;
    __syncthreads();
    for (int d = 1; d < 1024; d <<= 1) {
        int u = (t >= d) ? s[t - d] : 0;
        __syncthreads();
        s[t] += u;
        __syncthreads();
    }
    if (t < NS) bpre[t] = s[t] - v;
}

__global__ __launch_bounds__(256) void sb_apply(const int* __restrict__ hist,
                                                const int* __restrict__ bpre,
                                                int* __restrict__ base,
                                                int* __restrict__ bstart,
                                                int T, int NB, int NBLK, int E) {
    __shared__ int s[256];
    int i = blockIdx.x * 256 + threadIdx.x;
    int t = threadIdx.x;
    int v = 0;
    int b = 0, blk = 0;
    if (i < T) {
        b = i / NBLK;
        blk = i - b * NBLK;
        v = hist[blk * NB + b];
    }
    s[t] = v;
    __syncthreads();
    for (int d = 1; d < 256; d <<= 1) {
        int u = (t >= d) ? s[t - d] : 0;
        __syncthreads();
        s[t] += u;
        __syncthreads();
    }
    if (i < T) {
        int val = bpre[blockIdx.x] + s[t] - v;
        base[i] = val;
        if (blk == 0) bstart[b] = val;
        if (i == 0) bstart[NB] = E;
    }
}

__global__ __launch_bounds__(256) void scat_kernel(const int* __restrict__ src,
                                                   const int* __restrict__ dst,
                                                   const int* __restrict__ base,
                                                   unsigned int* __restrict__ recs,
                                                   int E, int NB, int NBLK) {
    __shared__ int cur[512];
    const int blk = blockIdx.x;
    for (int b = threadIdx.x; b < NB; b += 256) cur[b] = base[b * NBLK + blk];
    __syncthreads();
    const int e0 = blk * CHUNK;
    for (int i = threadIdx.x; i < CHUNK; i += 256) {
        int e = e0 + i;
        if (e >= E) continue;
        int d = dst[e];
        int b = d >> 8;
        int pos = atomicAdd(&cur[b], 1);
        recs[pos] = (unsigned int)src[e] | ((unsigned int)(d & 255) << 24);
    }
}

__global__ __launch_bounds__(256) void csr_kernel(const unsigned int* __restrict__ recs,
                                                  const int* __restrict__ bstart,
                                                  int* __restrict__ offs,
                                                  float* __restrict__ rdeg,
                                                  int* __restrict__ csr,
                                                  int N, int E) {
    __shared__ int cnt[256];
    __shared__ int sc[256];
    __shared__ int cur[256];
    const int b = blockIdx.x;
    const int t = threadIdx.x;
    const int s0 = bstart[b], s1 = bstart[b + 1];
    cnt[t] = 0;
    __syncthreads();
    for (int i = s0 + t; i < s1; i += 256) atomicAdd(&cnt[recs[i] >> 24], 1);
    __syncthreads();
    int v = cnt[t];
    sc[t] = v;
    __syncthreads();
    for (int d = 1; d < 256; d <<= 1) {
        int u = (t >= d) ? sc[t - d] : 0;
        __syncthreads();
        sc[t] += u;
        __syncthreads();
    }
    int excl = sc[t] - v;
    int node = b * 256 + t;
    if (node < N) {
        offs[node] = s0 + excl;
        rdeg[node] = 1.0f / (float)(v > 1 ? v : 1);
        if (node == N - 1) offs[N] = E;
    }
    cur[t] = s0 + excl;
    __syncthreads();
    for (int i = s0 + t; i < s1; i += 256) {
        unsigned int r = recs[i];
        int pos = atomicAdd(&cur[r >> 24], 1);
        csr[pos] = (int)(r & 0xFFFFFFu);
    }
}

// -------- mean aggregation from FP8 rows (128B/row), bf16 mean out -----------
// One node/wave; exact binary-decomposed edge groups (no wasted loads).

__global__ __launch_bounds__(256) void agg8_kernel(
        const unsigned char* __restrict__ h8, const int* __restrict__ offs,
        const int* __restrict__ csr, const float* __restrict__ rdeg,
        unsigned short* __restrict__ meanout, int N) {
    const int node = blockIdx.x * 4 + (threadIdx.x >> 6);
    const int lane = threadIdx.x & 63;
    if (node >= N) return;
    const int s0 = offs[node], s1 = offs[node + 1];
    const char* __restrict__ hb = (const char*)h8;
    const unsigned lane2 = (unsigned)lane * 2u;
    f32x2 acc = {0.f, 0.f};
    for (int base = s0; base < s1; base += 64) {
        const int cnt = min(64, s1 - base);
        const int boff = csr[base + min(lane, cnt - 1)] << 7;  // fp8 row byte offset
        int j = 0;
#define AGG8_GROUP(NG)                                                         \
        {                                                                      \
            unsigned o[NG];                                                    \
            _Pragma("unroll")                                                  \
            for (int k = 0; k < NG; ++k)                                       \
                o[k] = (unsigned)__shfl(boff, j + k, 64) + lane2;              \
            unsigned int v[NG];                                                \
            _Pragma("unroll")                                                  \
            for (int k = 0; k < NG; ++k)                                       \
                v[k] = *(const unsigned short*)(hb + o[k]);                    \
            _Pragma("unroll")                                                  \
            for (int k = 0; k < NG; ++k)                                       \
                acc += __builtin_amdgcn_cvt_pk_f32_fp8(v[k], false);           \
            j += NG;                                                           \
        }
        while (j + 16 <= cnt) AGG8_GROUP(16)
        if (cnt & 8) AGG8_GROUP(8)
        if (cnt & 4) AGG8_GROUP(4)
        if (cnt & 2) AGG8_GROUP(2)
        if (cnt & 1) AGG8_GROUP(1)
#undef AGG8_GROUP
    }
    float r = rdeg[node];
    unsigned int o = (unsigned int)f2b(acc.x * r) | ((unsigned int)f2b(acc.y * r) << 16);
    *(unsigned int*)&meanout[(size_t)node * NF + lane * 2] = o;
}

// ---- layer-2 final agg: out[i] = mean_j zl[j] + zr[i]  (fp32 out) -----------
// One node/wave; feature == lane (64 features); single-segment 128B row loads
// (64 lanes x ushort); no cross-lane reduce; binary-decomposed groups.

__global__ __launch_bounds__(256) void agg2_kernel(
        const unsigned short* __restrict__ z, const int* __restrict__ offs,
        const int* __restrict__ csr, const float* __restrict__ rdeg,
        float* __restrict__ out, int N) {
    const int node = blockIdx.x * 4 + (threadIdx.x >> 6);
    const int lane = threadIdx.x & 63;
    if (node >= N) return;
    const int s0 = offs[node], s1 = offs[node + 1];
    const char* __restrict__ zb = (const char*)z;
    const unsigned lane2 = (unsigned)lane * 2u;
    float acc = 0.f;
    for (int base = s0; base < s1; base += 64) {
        const int cnt = min(64, s1 - base);
        const int boff = csr[base + min(lane, cnt - 1)] << 8;  // z row byte offset (zl = first 128B)
        int j = 0;
#define AGG2_GROUP(NG)                                                         \
        {                                                                      \
            unsigned o[NG];                                                    \
            _Pragma("unroll")                                                  \
            for (int k = 0; k < NG; ++k)                                       \
                o[k] = (unsigned)__shfl(boff, j + k, 64) + lane2;              \
            unsigned int v[NG];                                                \
            _Pragma("unroll")                                                  \
            for (int k = 0; k < NG; ++k)                                       \
                v[k] = *(const unsigned short*)(zb + o[k]);                    \
            _Pragma("unroll")                                                  \
            for (int k = 0; k < NG; ++k)                                       \
                acc += __uint_as_float(v[k] << 16);                            \
            j += NG;                                                           \
        }
        while (j + 16 <= cnt) AGG2_GROUP(16)
        if (cnt & 8) AGG2_GROUP(8)
        if (cnt & 4) AGG2_GROUP(4)
        if (cnt & 2) AGG2_GROUP(2)
        if (cnt & 1) AGG2_GROUP(1)
#undef AGG2_GROUP
    }
    float r = rdeg[node];
    unsigned int vr = *(const unsigned short*)(zb + (size_t)node * 256 + 128 + lane2);
    out[(size_t)node * 64 + lane] = acc * r + __uint_as_float(vr << 16);
}

// ------- MFMA GEMM (layers 0/1): out = [mean|h] @ Wcat^T + b, relu, bf16 out ---
// OUT8: additionally emit fp8 rows of the output (for next layer's gather).

template <int FOUT, bool RELU, bool OUT8>
__global__ __launch_bounds__(256) void gemm_kernel(
        const unsigned short* __restrict__ Abuf,   // mean [N][128] bf16
        const unsigned short* __restrict__ Hbuf,   // root [N][128] bf16
        const unsigned short* __restrict__ Wcat,   // [FOUT][256] bf16
        const float* __restrict__ bias,            // [FOUT] fp32
        unsigned short* __restrict__ outb,
        unsigned char* __restrict__ out8,
        int N) {
    __shared__ unsigned short As[128 * 256];

    const int tid = threadIdx.x, wid = tid >> 6, lane = tid & 63;
    const int m0 = blockIdx.x * 128;
    char* Ac = (char*)As;
    const char* Ab = (const char*)Abuf;
    const char* Hb = (const char*)Hbuf;
    const char* Wb = (const char*)Wcat;

#pragma unroll
    for (int i = 0; i < 16; ++i) {
        int off = wid * 16384 + i * 1024 + lane * 16;
        int row = off >> 9, c = off & 511;
        int c2 = c ^ ((row & 7) << 4);
        const char* srcp = (c2 < 256) ? (Ab + (size_t)(m0 + row) * 256 + c2)
                                      : (Hb + (size_t)(m0 + row) * 256 + (c2 - 256));
        gld_lds16(srcp, Ac + wid * 16384 + i * 1024);
    }
    asm volatile("s_waitcnt vmcnt(0)" ::: "memory");
    __syncthreads();

    constexpr int MI = (FOUT == 128) ? 4 : 2;
    constexpr int NI = 4;
    const int lm = lane & 15, ko = lane >> 4;
    const int wmBase = (FOUT == 128) ? (wid >> 1) * 64 : wid * 32;
    const int wnBase = (FOUT == 128) ? (wid & 1) * 64 : 0;

    f32x4 acc[MI][NI];
#pragma unroll
    for (int i = 0; i < MI; ++i)
#pragma unroll
        for (int j = 0; j < NI; ++j)
            acc[i][j] = (f32x4){0.f, 0.f, 0.f, 0.f};

#pragma unroll
    for (int ks = 0; ks < 8; ++ks) {
        const int kb = ks * 64 + ko * 16;
        bf16x8 a[MI], b[NI];
#pragma unroll
        for (int j = 0; j < NI; ++j) {
            int row = wnBase + j * 16 + lm;
            b[j] = *(const bf16x8*)(Wb + row * 512 + kb);   // direct global (hot)
        }
#pragma unroll
        for (int i = 0; i < MI; ++i) {
            int row = wmBase + i * 16 + lm;
            a[i] = *(const bf16x8*)(Ac + row * 512 + (kb ^ ((row & 7) << 4)));
        }
#pragma unroll
        for (int i = 0; i < MI; ++i)
#pragma unroll
            for (int j = 0; j < NI; ++j)
                acc[i][j] = __builtin_amdgcn_mfma_f32_16x16x32_bf16(b[j], a[i], acc[i][j], 0, 0, 0);
    }

#pragma unroll
    for (int i = 0; i < MI; ++i) {
        const int node = m0 + wmBase + i * 16 + lm;
        if (node < N) {
#pragma unroll
            for (int j = 0; j < NI; ++j) {
                const int col0 = wnBase + j * 16 + ko * 4;
                const float4 bv = *(const float4*)&bias[col0];
                float v0 = acc[i][j][0] + bv.x;
                float v1 = acc[i][j][1] + bv.y;
                float v2 = acc[i][j][2] + bv.z;
                float v3 = acc[i][j][3] + bv.w;
                if (RELU) {
                    v0 = fmaxf(v0, 0.f); v1 = fmaxf(v1, 0.f);
                    v2 = fmaxf(v2, 0.f); v3 = fmaxf(v3, 0.f);
                }
                uint2 o;
                o.x = (unsigned int)f2b(v0) | ((unsigned int)f2b(v1) << 16);
                o.y = (unsigned int)f2b(v2) | ((unsigned int)f2b(v3) << 16);
                *(uint2*)&outb[(size_t)node * FOUT + col0] = o;
                if (OUT8) {
                    unsigned p = __builtin_amdgcn_cvt_pk_fp8_f32(v0, v1, 0, false);
                    p = __builtin_amdgcn_cvt_pk_fp8_f32(v2, v3, p, true);
                    *(unsigned int*)&out8[(size_t)node * FOUT + col0] = p;
                }
            }
        }
    }
}

// ---------- MFMA GEMM (layer 2): z = h @ Wst^T + bst  (K=128, bf16 out) -------

__global__ __launch_bounds__(256) void gemmz_kernel(
        const unsigned short* __restrict__ A,    // [N][128] bf16
        const unsigned short* __restrict__ W,    // [128][128] bf16
        const float* __restrict__ bias,          // [128] fp32
        unsigned short* __restrict__ outb,       // [N][128] bf16
        int N) {
    __shared__ unsigned short As[128 * 128];

    const int tid = threadIdx.x, wid = tid >> 6, lane = tid & 63;
    const int m0 = blockIdx.x * 128;
    char* Ac = (char*)As;
    const char* Ab = (const char*)A;
    const char* Wb = (const char*)W;

#pragma unroll
    for (int i = 0; i < 8; ++i) {
        int off = wid * 8192 + i * 1024 + lane * 16;
        int row = off >> 8, c = off & 255;
        int c2 = c ^ ((row & 7) << 4);
        gld_lds16(Ab + (size_t)(m0 + row) * 256 + c2, Ac + wid * 8192 + i * 1024);
    }
    asm volatile("s_waitcnt vmcnt(0)" ::: "memory");
    __syncthreads();

    const int lm = lane & 15, ko = lane >> 4;
    const int wmBase = (wid >> 1) * 64;
    const int wnBase = (wid & 1) * 64;

    f32x4 acc[4][4];
#pragma unroll
    for (int i = 0; i < 4; ++i)
#pragma unroll
        for (int j = 0; j < 4; ++j)
            acc[i][j] = (f32x4){0.f, 0.f, 0.f, 0.f};

#pragma unroll
    for (int ks = 0; ks < 4; ++ks) {
        const int kb = ks * 64 + ko * 16;
        bf16x8 a[4], b[4];
#pragma unroll
        for (int j = 0; j < 4; ++j) {
            int row = wnBase + j * 16 + lm;
            b[j] = *(const bf16x8*)(Wb + row * 256 + kb);   // direct global (hot)
        }
#pragma unroll
        for (int i = 0; i < 4; ++i) {
            int row = wmBase + i * 16 + lm;
            a[i] = *(const bf16x8*)(Ac + row * 256 + (kb ^ ((row & 7) << 4)));
        }
#pragma unroll
        for (int i = 0; i < 4; ++i)
#pragma unroll
            for (int j = 0; j < 4; ++j)
                acc[i][j] = __builtin_amdgcn_mfma_f32_16x16x32_bf16(b[j], a[i], acc[i][j], 0, 0, 0);
    }

#pragma unroll
    for (int i = 0; i < 4; ++i) {
        const int node = m0 + wmBase + i * 16 + lm;
        if (node < N) {
#pragma unroll
            for (int j = 0; j < 4; ++j) {
                const int col0 = wnBase + j * 16 + ko * 4;
                const float4 bv = *(const float4*)&bias[col0];
                uint2 o;
                o.x = (unsigned int)f2b(acc[i][j][0] + bv.x) |
                      ((unsigned int)f2b(acc[i][j][1] + bv.y) << 16);
                o.y = (unsigned int)f2b(acc[i][j][2] + bv.z) |
                      ((unsigned int)f2b(acc[i][j][3] + bv.w) << 16);
                *(uint2*)&outb[(size_t)node * 128 + col0] = o;
            }
        }
    }
}

// ---------------- launch ----------------

extern "C" void kernel_launch(void* const* d_in, const int* in_sizes, int n_in,
                              void* d_out, int out_size, void* d_ws, size_t ws_size,
                              hipStream_t stream) {
    const float* x   = (const float*)d_in[0];
    const int*   ei  = (const int*)d_in[1];
    const float* Wl0 = (const float*)d_in[2];
    const float* Wr0 = (const float*)d_in[3];
    const float* b0  = (const float*)d_in[4];
    const float* Wl1 = (const float*)d_in[5];
    const float* Wr1 = (const float*)d_in[6];
    const float* b1  = (const float*)d_in[7];
    const float* Wl2 = (const float*)d_in[8];
    const float* Wr2 = (const float*)d_in[9];
    const float* b2  = (const float*)d_in[10];
    float* out = (float*)d_out;

    const int N = in_sizes[0] / NF;
    const int E = in_sizes[1] / 2;
    const int* srcv = ei;
    const int* dstv = ei + E;

    const int NB   = (N + 255) >> 8;
    const int NBLK = (E + CHUNK - 1) / CHUNK;
    const int T    = NB * NBLK;
    const int NS   = (T + 255) / 256;

    char* w = (char*)d_ws;
    auto alloc = [&](size_t bytes) {
        void* p = (void*)w;
        w += (bytes + 255) & ~(size_t)255;
        return p;
    };
    unsigned short* xb   = (unsigned short*)alloc((size_t)N * NF * 2);
    unsigned short* h1b  = (unsigned short*)alloc((size_t)N * NF * 2);
    unsigned short* h2b  = (unsigned short*)alloc((size_t)N * NF * 2);
    unsigned short* mb   = (unsigned short*)alloc((size_t)N * NF * 2);
    // fp8 region (25.6 MB): x8 + h18 while live; z2b aliases it afterwards
    unsigned char*  u8   = (unsigned char*)alloc((size_t)N * NF * 2);
    unsigned char*  x8   = u8;                       // [N][128] fp8
    unsigned char*  h18  = u8 + (size_t)N * NF;      // [N][128] fp8
    unsigned short* z2b  = (unsigned short*)u8;      // [N][128] bf16 (after x8/h18 dead)
    unsigned short* Wc0  = (unsigned short*)alloc((size_t)128 * 256 * 2);
    unsigned short* Wc1  = (unsigned short*)alloc((size_t)128 * 256 * 2);
    unsigned short* Wst2 = (unsigned short*)alloc((size_t)128 * 128 * 2);
    float*          bst2 = (float*)alloc((size_t)128 * 4);
    int*   offs   = (int*)alloc((size_t)(N + 1) * 4);
    int*   csr    = (int*)alloc((size_t)E * 4);
    float* rdeg   = (float*)alloc((size_t)N * 4);
    unsigned int* recs = (unsigned int*)alloc((size_t)E * 4);
    int*   hist   = (int*)alloc((size_t)T * 4);
    int*   base   = (int*)alloc((size_t)T * 4);
    int*   bstart = (int*)alloc((size_t)(NB + 1) * 4);
    int*   sb1    = (int*)alloc((size_t)1024 * 4);
    int*   sb2    = (int*)alloc((size_t)1024 * 4);

    const int n4 = N * NF / 4;
    const int bCvt = (n4 + 255) / 256;
    const int bW0  = bCvt + 64;            // wcat0: 16384/256
    const int bW1  = bW0 + 64;             // wcat1
    const int bWs  = bW1 + 32;             // wstack: 8192/256
    const int bTot = bWs + NBLK;           // + hist

    prep_kernel<<<bTot, 256, 0, stream>>>(x, xb, x8, n4,
                                          Wl0, Wr0, Wc0, Wl1, Wr1, Wc1,
                                          Wl2, Wr2, b2, Wst2, bst2,
                                          dstv, hist, E, NB,
                                          bCvt, bW0, bW1, bWs);
    sb_sum<<<NS, 256, 0, stream>>>(hist, sb1, T, NB, NBLK);
    sb_scan<<<1, 1024, 0, stream>>>(sb1, sb2, NS);
    sb_apply<<<NS, 256, 0, stream>>>(hist, sb2, base, bstart, T, NB, NBLK, E);
    scat_kernel<<<NBLK, 256, 0, stream>>>(srcv, dstv, base, recs, E, NB, NBLK);
    csr_kernel<<<NB, 256, 0, stream>>>(recs, bstart, offs, rdeg, csr, N, E);

    const int ab = (N + 3) / 4;
    const int gb = (N + 127) / 128;

    // layer 0: mean from fp8 x; gemm also emits fp8 h1 for next gather
    agg8_kernel<<<ab, 256, 0, stream>>>(x8, offs, csr, rdeg, mb, N);
    gemm_kernel<128, true, true><<<gb, 256, 0, stream>>>(mb, xb, Wc0, b0, h1b, h18, N);

    // layer 1: mean from fp8 h1, root bf16 h1
    agg8_kernel<<<ab, 256, 0, stream>>>(h18, offs, csr, rdeg, mb, N);
    gemm_kernel<128, true, false><<<gb, 256, 0, stream>>>(mb, h1b, Wc1, b1, h2b, nullptr, N);

    // layer 2: transform-first (bf16), fused final agg
    gemmz_kernel<<<gb, 256, 0, stream>>>(h2b, Wst2, bst2, z2b, N);
    agg2_kernel<<<ab, 256, 0, stream>>>(z2b, offs, csr, rdeg, out, N);
}